// Round 1
// baseline (2371.514 us; speedup 1.0000x reference)
//
#include <hip/hip_runtime.h>

typedef unsigned int uint;
typedef unsigned short u16;

#define BB 4
#define CE 384
#define DD 512
#define LL 8
#define HH 16
#define MM 2048
#define NJ 163
#define TOK 4096
#define BKQ 64
#define QH 256
#define OUTW 1486

typedef __attribute__((ext_vector_type(8))) short short8;
typedef __attribute__((ext_vector_type(4))) float float4v;

static __device__ __forceinline__ u16 f2bf(float f){
  union { float f; uint u; } c; c.f = f;
  uint u = c.u;
  return (u16)((u + 0x7FFFu + ((u >> 16) & 1u)) >> 16);
}
static __device__ __forceinline__ float wred_sum(float v){
  for (int o = 32; o; o >>= 1) v += __shfl_xor(v, o, 64);
  return v;
}
static __device__ __forceinline__ float wred_max(float v){
  for (int o = 32; o; o >>= 1) v = fmaxf(v, __shfl_xor(v, o, 64));
  return v;
}

// ---------------- NMS + top-k (exact fp32, stable ties) ----------------
__global__ __launch_bounds__(256) void k_nms_topk(const float* __restrict__ scores,
    int* __restrict__ oidx, float* __restrict__ omask, float* __restrict__ ocol, float* __restrict__ orow)
{
  int b = blockIdx.x, t = threadIdx.x;
  __shared__ float sraw[4096];
  __shared__ float snms[4096];
  __shared__ float bv[256];
  __shared__ int   bi[256];
  const float* sp = scores + (size_t)b * 4096;
  for (int i = t; i < 4096; i += 256) sraw[i] = sp[i];
  __syncthreads();
  for (int i = t; i < 4096; i += 256){
    int r = i >> 6, c = i & 63;
    float mx = -1e30f;
    for (int dr = -1; dr <= 1; dr++){
      int rr = r + dr; if (rr < 0 || rr > 63) continue;
      for (int dc = -1; dc <= 1; dc++){
        int cc = c + dc; if (cc < 0 || cc > 63) continue;
        mx = fmaxf(mx, sraw[rr*64+cc]);
      }
    }
    snms[i] = (sraw[i] == mx) ? sraw[i] : 0.0f;
  }
  __syncthreads();
  for (int iter = 0; iter < 16; iter++){
    float best = -1e30f; int bidx = 1 << 30;
    for (int i = t; i < 4096; i += 256){
      float v = snms[i];
      if (v > best){ best = v; bidx = i; }
    }
    bv[t] = best; bi[t] = bidx;
    __syncthreads();
    for (int s = 128; s > 0; s >>= 1){
      if (t < s){
        if (bv[t+s] > bv[t] || (bv[t+s] == bv[t] && bi[t+s] < bi[t])){ bv[t] = bv[t+s]; bi[t] = bi[t+s]; }
      }
      __syncthreads();
    }
    if (t == 0){
      int idx = bi[0]; float val = bv[0];
      oidx[b*16+iter] = idx;
      omask[b*16+iter] = (val >= 0.3f) ? 1.f : 0.f;
      ocol[b*16+iter] = (float)(idx & 63);
      orow[b*16+iter] = (float)(idx >> 6);
      snms[idx] = -1e30f;
    }
    __syncthreads();
  }
}

// ---------------- fp32 -> bf16 convert ----------------
__global__ __launch_bounds__(256) void k_cvt_bf16(const float* __restrict__ in, u16* __restrict__ out, int n4){
  int i = blockIdx.x*256 + threadIdx.x;
  int stride = gridDim.x*256;
  for (int j = i; j < n4; j += stride){
    float4 v = ((const float4*)in)[j];
    ushort4 o;
    o.x = f2bf(v.x); o.y = f2bf(v.y); o.z = f2bf(v.z); o.w = f2bf(v.w);
    ((ushort4*)out)[j] = o;
  }
}

// ---------------- transpose+convert fp32(R,C) -> bf16(C,R) ----------------
__global__ __launch_bounds__(256) void k_tconv_f2b(const float* __restrict__ in, u16* __restrict__ out, int R, int C){
  __shared__ float tile[32][33];
  int c0 = blockIdx.x*32, r0 = blockIdx.y*32;
  int tx = threadIdx.x & 31, ty = threadIdx.x >> 5;
  for (int i = 0; i < 32; i += 8) tile[ty+i][tx] = in[(size_t)(r0+ty+i)*C + c0+tx];
  __syncthreads();
  for (int i = 0; i < 32; i += 8) out[(size_t)(c0+ty+i)*R + r0+tx] = f2bf(tile[tx][ty+i]);
}

// ---------------- bf16 transpose (R,C) -> (C,R), batched in z ----------------
__global__ __launch_bounds__(256) void k_transp_b(const u16* __restrict__ in, u16* __restrict__ out, int R, int C){
  in  += (size_t)blockIdx.z * R * C;
  out += (size_t)blockIdx.z * R * C;
  __shared__ u16 tile[32][33];
  int c0 = blockIdx.x*32, r0 = blockIdx.y*32;
  int tx = threadIdx.x & 31, ty = threadIdx.x >> 5;
  for (int i = 0; i < 32; i += 8) tile[ty+i][tx] = in[(size_t)(r0+ty+i)*C + c0+tx];
  __syncthreads();
  for (int i = 0; i < 32; i += 8) out[(size_t)(c0+ty+i)*R + r0+tx] = tile[tx][ty+i];
}

// ---------------- MFMA bf16 GEMM, C = A(MxK) * Bt(NxK)^T ----------------
// EPI 0: store f32   EPI 1: atomicAdd f32 (split-K)   EPI 2: embed epilogue -> bf16
template<int EPI>
__global__ __launch_bounds__(256) void k_gemm_bt(
    const u16* __restrict__ A, const u16* __restrict__ Bt,
    float* __restrict__ C, u16* __restrict__ Cb,
    const float* __restrict__ ep1, const float* __restrict__ ep2,
    int Kslice, int lda, int ldb, int ldc,
    long sA, long sB, long sC, int ksplit)
{
  int bz = blockIdx.z;
  int batch = bz / ksplit, ks = bz - batch*ksplit;
  const u16* Ab = A + (size_t)batch*sA + (size_t)ks*Kslice;
  const u16* Bb = Bt + (size_t)batch*sB + (size_t)ks*Kslice;
  int m0 = blockIdx.y*128, n0 = blockIdx.x*128;
  __shared__ __align__(16) u16 As[128*32];
  __shared__ __align__(16) u16 Bs[128*32];
  int t = threadIdx.x, lane = t & 63, wave = t >> 6;
  int wr = wave >> 1, wc = wave & 1;
  int lr = lane & 15, lk = lane >> 4;
  int srow = t >> 2, scol = (t & 3) * 8;
  float4v acc[4][4];
  float4v z4 = {0.f, 0.f, 0.f, 0.f};
  #pragma unroll
  for (int i = 0; i < 4; i++)
    #pragma unroll
    for (int j = 0; j < 4; j++) acc[i][j] = z4;

  for (int kt = 0; kt < Kslice; kt += 32){
    int4 a0 = *(const int4*)(Ab + (size_t)(m0+srow)*lda + kt + scol);
    int4 a1 = *(const int4*)(Ab + (size_t)(m0+64+srow)*lda + kt + scol);
    int4 b0 = *(const int4*)(Bb + (size_t)(n0+srow)*ldb + kt + scol);
    int4 b1 = *(const int4*)(Bb + (size_t)(n0+64+srow)*ldb + kt + scol);
    __syncthreads();
    *(int4*)&As[srow*32 + scol] = a0;
    *(int4*)&As[(64+srow)*32 + scol] = a1;
    *(int4*)&Bs[srow*32 + scol] = b0;
    *(int4*)&Bs[(64+srow)*32 + scol] = b1;
    __syncthreads();
    short8 af[4], bf[4];
    #pragma unroll
    for (int i = 0; i < 4; i++) af[i] = *(const short8*)&As[(wr*64 + i*16 + lr)*32 + lk*8];
    #pragma unroll
    for (int j = 0; j < 4; j++) bf[j] = *(const short8*)&Bs[(wc*64 + j*16 + lr)*32 + lk*8];
    #pragma unroll
    for (int i = 0; i < 4; i++)
      #pragma unroll
      for (int j = 0; j < 4; j++)
        acc[i][j] = __builtin_amdgcn_mfma_f32_16x16x32_bf16(af[i], bf[j], acc[i][j], 0, 0, 0);
  }
  #pragma unroll
  for (int i = 0; i < 4; i++){
    int rbase = m0 + wr*64 + i*16 + lk*4;
    #pragma unroll
    for (int j = 0; j < 4; j++){
      int cc = n0 + wc*64 + j*16 + lr;
      #pragma unroll
      for (int jj = 0; jj < 4; jj++){
        float v = acc[i][j][jj];
        int rr = rbase + jj;
        if (EPI == 0) C[(size_t)batch*sC + (size_t)rr*ldc + cc] = v;
        else if (EPI == 1) atomicAdd(C + (size_t)batch*sC + (size_t)rr*ldc + cc, v);
        else {
          float vv = v + ep1[cc] + ep2[(size_t)(rr & 4095)*DD + cc];
          Cb[(size_t)rr*ldc + cc] = f2bf(vv);
        }
      }
    }
  }
}

// ---------------- gather + fp32 embed for the 64 selected tokens ----------------
__global__ __launch_bounds__(256) void k_gather(const float* __restrict__ feat, const float* __restrict__ Wtok,
    const float* __restrict__ btok, const float* __restrict__ pos_emb, const int* __restrict__ oidx,
    float* __restrict__ x)
{
  int bq = blockIdx.x, b = bq >> 4;
  int tok = oidx[bq];
  __shared__ float fs[CE];
  const float* fr = feat + ((size_t)b*TOK + tok) * CE;
  for (int i = threadIdx.x; i < CE; i += 256) fs[i] = fr[i];
  __syncthreads();
  for (int d = threadIdx.x; d < DD; d += 256){
    float acc = btok[d] + pos_emb[(size_t)tok*DD + d];
    for (int i = 0; i < CE; i++) acc += fs[i] * Wtok[(size_t)i*DD + d];
    x[(size_t)bq*DD + d] = acc;
  }
}

// ---------------- LayerNorm over 64 rows ----------------
__global__ __launch_bounds__(256) void k_ln64(const float* __restrict__ x, const float* __restrict__ g,
    const float* __restrict__ b, float* __restrict__ h)
{
  int bq = blockIdx.x, t = threadIdx.x;
  const float* xr = x + (size_t)bq*DD;
  float a0 = xr[t], a1 = xr[t+256];
  __shared__ float sr[4];
  float s = wred_sum(a0 + a1);
  if ((t & 63) == 0) sr[t >> 6] = s;
  __syncthreads();
  float mu = (sr[0]+sr[1]+sr[2]+sr[3]) * (1.f/DD);
  float d0 = a0 - mu, d1 = a1 - mu;
  __syncthreads();
  float q = wred_sum(d0*d0 + d1*d1);
  if ((t & 63) == 0) sr[t >> 6] = q;
  __syncthreads();
  float var = (sr[0]+sr[1]+sr[2]+sr[3]) * (1.f/DD);
  float inv = rsqrtf(var + 1e-5f);
  h[(size_t)bq*DD + t]     = d0*inv*g[t]     + b[t];
  h[(size_t)bq*DD + t+256] = d1*inv*g[t+256] + b[t+256];
}

// ---------------- small fp32 GEMM: C(Mx N) = A(MxK) @ B(KxN) ----------------
// ACT 0 none / 1 relu / 2 gelu.  RES 0 store / 1 += / 2 atomicAdd (split-K via grid.z)
template<int ACT, int RES>
__global__ __launch_bounds__(256) void k_smallmm(
    const float* __restrict__ A, const float* __restrict__ Bm,
    const float* __restrict__ bias, float* __restrict__ C,
    int N, int K, int lda, int ldb, int ldc, float alpha)
{
  __shared__ float As[16*256];
  int t = threadIdx.x;
  int m0 = blockIdx.y * 16;
  int col = blockIdx.x * 64 + (t & 63);
  int w = t >> 6;
  int kper = K / gridDim.z;
  int kbeg = blockIdx.z * kper;
  float acc[4] = {0.f, 0.f, 0.f, 0.f};
  for (int kc = kbeg; kc < kbeg + kper; kc += 256){
    __syncthreads();
    for (int idx = t; idx < 4096; idx += 256){
      int r = idx >> 8, k = idx & 255;
      As[idx] = A[(size_t)(m0+r)*lda + kc + k];
    }
    __syncthreads();
    if (col < N){
      #pragma unroll 4
      for (int k = 0; k < 256; k++){
        float bv = Bm[(size_t)(kc+k)*ldb + col];
        acc[0] += As[(w*4+0)*256 + k] * bv;
        acc[1] += As[(w*4+1)*256 + k] * bv;
        acc[2] += As[(w*4+2)*256 + k] * bv;
        acc[3] += As[(w*4+3)*256 + k] * bv;
      }
    }
  }
  if (col < N){
    float bsv = (bias && blockIdx.z == 0) ? bias[col] : 0.f;
    #pragma unroll
    for (int i = 0; i < 4; i++){
      float v = acc[i]*alpha + bsv;
      if (ACT == 1) v = fmaxf(v, 0.f);
      else if (ACT == 2) v = 0.5f*v*(1.f + tanhf(0.7978845608028654f*(v + 0.044715f*v*v*v)));
      size_t o = (size_t)(m0 + w*4 + i)*ldc + col;
      if (RES == 0) C[o] = v;
      else if (RES == 1) C[o] += v;
      else atomicAdd(&C[o], v);
    }
  }
}

// ---------------- z[bq][h][d] = sum_dh u[bq][h*32+dh] * Wk[d][h*32+dh]  (bf16 out) ----------------
__global__ __launch_bounds__(256) void k_zker(const float* __restrict__ u, const float* __restrict__ Wk, u16* __restrict__ z){
  int ds = blockIdx.x, h = blockIdx.y, t = threadIdx.x;
  __shared__ float us[64*33];
  __shared__ float wks[128*33];
  for (int idx = t; idx < 2048; idx += 256){ int bq = idx >> 5, dh = idx & 31; us[bq*33+dh] = u[(size_t)bq*DD + h*32 + dh]; }
  for (int idx = t; idx < 4096; idx += 256){ int r = idx >> 5, dh = idx & 31; wks[r*33+dh] = Wk[(size_t)(ds*128+r)*DD + h*32 + dh]; }
  __syncthreads();
  for (int oi = t; oi < 8192; oi += 256){
    int d = oi & 127, bq = oi >> 7;
    float acc = 0.f;
    #pragma unroll
    for (int dh = 0; dh < 32; dh++) acc += us[bq*33+dh] * wks[d*33+dh];
    z[((size_t)bq*HH + h)*DD + ds*128 + d] = f2bf(acc);
  }
}

// ---------------- softmax over 4096, fp32 in -> bf16 probs ----------------
__global__ __launch_bounds__(256) void k_softmax(const float* __restrict__ lg, u16* __restrict__ att){
  int row = blockIdx.x, t = threadIdx.x;
  const float* p = lg + (size_t)row*TOK;
  float v[16]; float mx = -1e30f;
  #pragma unroll
  for (int i = 0; i < 16; i++){ v[i] = p[t + i*256]; mx = fmaxf(mx, v[i]); }
  mx = wred_max(mx);
  __shared__ float sm[4]; __shared__ float ssum[4];
  if ((t & 63) == 0) sm[t >> 6] = mx;
  __syncthreads();
  mx = fmaxf(fmaxf(sm[0], sm[1]), fmaxf(sm[2], sm[3]));
  float s = 0.f;
  #pragma unroll
  for (int i = 0; i < 16; i++){ v[i] = expf(v[i] - mx); s += v[i]; }
  s = wred_sum(s);
  if ((t & 63) == 0) ssum[t >> 6] = s;
  __syncthreads();
  s = ssum[0]+ssum[1]+ssum[2]+ssum[3];
  float inv = 1.f / s;
  u16* q = att + (size_t)row*TOK;
  #pragma unroll
  for (int i = 0; i < 16; i++) q[t + i*256] = f2bf(v[i]*inv);
}

// ---------------- o_pre[bq][h*32+dh] = sum_D c[bq][h][D] * Wv[D][h*32+dh] ----------------
__global__ __launch_bounds__(256) void k_ovp(const float* __restrict__ c, const float* __restrict__ Wv, float* __restrict__ op){
  int bg = blockIdx.x, h = blockIdx.y, t = threadIdx.x;
  __shared__ float wvs[128*33];
  __shared__ float cs[16*129];
  int dh = t & 31, bl = t >> 5;
  float acc0 = 0.f, acc1 = 0.f;
  for (int Dc = 0; Dc < DD; Dc += 128){
    __syncthreads();
    for (int idx = t; idx < 4096; idx += 256){ int r = idx >> 5, q = idx & 31; wvs[r*33+q] = Wv[(size_t)(Dc+r)*DD + h*32 + q]; }
    for (int idx = t; idx < 2048; idx += 256){ int r = idx >> 7, k = idx & 127; cs[r*129+k] = c[((size_t)(bg*16+r)*HH + h)*DD + Dc + k]; }
    __syncthreads();
    #pragma unroll 4
    for (int k = 0; k < 128; k++){
      float wv = wvs[k*33+dh];
      acc0 += cs[bl*129 + k] * wv;
      acc1 += cs[(bl+8)*129 + k] * wv;
    }
  }
  op[(size_t)(bg*16+bl)*DD + h*32 + dh] = acc0;
  op[(size_t)(bg*16+bl+8)*DD + h*32 + dh] = acc1;
}

// ---------------- constants for pose head ----------------
__global__ __launch_bounds__(256) void k_cvec(const float* __restrict__ pW1, const float* __restrict__ pb1,
    const float* __restrict__ ibp, float* __restrict__ cvec)
{
  int d = blockIdx.x*256 + threadIdx.x;
  float acc = pb1[d];
  for (int i = 0; i < NJ*6; i++) acc += ibp[i] * pW1[(size_t)(DD+i)*DD + d];
  cvec[d] = acc;
}
__global__ __launch_bounds__(256) void k_cvec2(const float* __restrict__ pb2, const float* __restrict__ ibp, float* __restrict__ cv){
  int j = blockIdx.x*256 + threadIdx.x;
  if (j < NJ*6) cv[j] = pb2[j] + ibp[j];
}

// ---------------- final heads + Gram-Schmidt + assembly ----------------
__global__ __launch_bounds__(256) void k_final(
    const float* __restrict__ h_off, const float* __restrict__ h_d, const float* __restrict__ h_s,
    const float* __restrict__ rot6d,
    const float* __restrict__ offW2, const float* __restrict__ offb2,
    const float* __restrict__ dW2, const float* __restrict__ db2,
    const float* __restrict__ sW2, const float* __restrict__ sb2,
    const float* __restrict__ K_cam, const float* __restrict__ useful,
    const float* __restrict__ maskf, const float* __restrict__ colf, const float* __restrict__ rowf,
    float* __restrict__ out)
{
  int bq = blockIdx.x, t = threadIdx.x, b = bq >> 4;
  float po0 = 0.f, po1 = 0.f, pd = 0.f, ps[11];
  #pragma unroll
  for (int j = 0; j < 11; j++) ps[j] = 0.f;
  for (int i = t; i < DD; i += 256){
    float ho = h_off[(size_t)bq*DD + i];
    float hd = h_d[(size_t)bq*DD + i];
    float hs = h_s[(size_t)bq*DD + i];
    po0 += ho*offW2[i*2]; po1 += ho*offW2[i*2+1];
    pd += hd*dW2[i];
    #pragma unroll
    for (int j = 0; j < 11; j++) ps[j] += hs*sW2[i*11+j];
  }
  __shared__ float sred[4][14];
  __shared__ float sout[14];
  int wv = t >> 6, ln = t & 63;
  float vals[14];
  vals[0] = po0; vals[1] = po1; vals[2] = pd;
  #pragma unroll
  for (int j = 0; j < 11; j++) vals[3+j] = ps[j];
  #pragma unroll
  for (int kk = 0; kk < 14; kk++){
    float r = wred_sum(vals[kk]);
    if (ln == 0) sred[wv][kk] = r;
  }
  __syncthreads();
  if (t < 14) sout[t] = sred[0][t]+sred[1][t]+sred[2][t]+sred[3][t];
  __syncthreads();
  float m = maskf[bq];
  if (t == 0){
    float off0 = sout[0] + offb2[0], off1 = sout[1] + offb2[1];
    float draw = sout[2] + db2[0];
    float l0 = (colf[bq] + 0.5f + off0) * 14.0f;
    float l1 = (rowf[bq] + 0.5f + off1) * 14.0f;
    float fx = K_cam[b*9+0], cx = K_cam[b*9+2], fy = K_cam[b*9+4], cy = K_cam[b*9+5];
    float dist = fx / fmaxf(expf(draw), 1e-5f);
    float tx = (l0 - cx) / fx * dist, ty = (l1 - cy) / fy * dist;
    float* o = out + (size_t)bq*OUTW;
    o[0] = l0*m; o[1] = l1*m; o[2] = off0*m; o[3] = off1*m; o[4] = dist*m;
    o[5] = tx*m; o[6] = ty*m; o[7] = dist*m;
    #pragma unroll
    for (int j = 0; j < 11; j++){ float sp = sout[3+j] + sb2[j]; o[8+j] = m / (1.f + expf(-sp)); }
  }
  if (t < NJ){
    const float* rp = rot6d + (size_t)bq*(NJ*6) + t*6;
    float a0 = rp[0], b0 = rp[1], a1 = rp[2], b1 = rp[3], a2 = rp[4], b2 = rp[5];
    float n0 = sqrtf(a0*a0 + a1*a1 + a2*a2);
    float i0 = 1.f / (n0 + 1e-8f);
    float u00 = a0*i0, u01 = a1*i0, u02 = a2*i0;
    float dt = b0*u00 + b1*u01 + b2*u02;
    float v0 = b0 - dt*u00, v1 = b1 - dt*u01, v2 = b2 - dt*u02;
    float n1 = sqrtf(v0*v0 + v1*v1 + v2*v2);
    float i1 = 1.f / (n1 + 1e-8f);
    float u10 = v0*i1, u11 = v1*i1, u12 = v2*i1;
    float u20 = u01*u12 - u02*u11;
    float u21 = u02*u10 - u00*u12;
    float u22 = u00*u11 - u01*u10;
    float um = useful[t], om = 1.f - um;
    float R00 = um*u00 + om, R01 = um*u10,      R02 = um*u20;
    float R10 = um*u01,      R11 = um*u11 + om, R12 = um*u21;
    float R20 = um*u02,      R21 = um*u12,      R22 = um*u22 + om;
    float* o = out + (size_t)bq*OUTW + 19 + t*9;
    o[0] = R00*m; o[1] = R01*m; o[2] = R02*m;
    o[3] = R10*m; o[4] = R11*m; o[5] = R12*m;
    o[6] = R20*m; o[7] = R21*m; o[8] = R22*m;
  }
}

extern "C" void kernel_launch(void* const* d_in, const int* in_sizes, int n_in,
                              void* d_out, int out_size, void* d_ws, size_t ws_size,
                              hipStream_t stream)
{
  const float* feat   = (const float*)d_in[0];
  const float* scores = (const float*)d_in[1];
  const float* K_cam  = (const float*)d_in[2];
  const float* pos_emb= (const float*)d_in[3];
  const float* Wtok   = (const float*)d_in[4];
  const float* btok   = (const float*)d_in[5];
  const float* Wq     = (const float*)d_in[6];
  const float* Wk     = (const float*)d_in[7];
  const float* Wv     = (const float*)d_in[8];
  const float* Wo     = (const float*)d_in[9];
  const float* g1     = (const float*)d_in[10];
  const float* b1n    = (const float*)d_in[11];
  const float* W1     = (const float*)d_in[12];
  const float* bf1    = (const float*)d_in[13];
  const float* W2     = (const float*)d_in[14];
  const float* bf2    = (const float*)d_in[15];
  const float* g2     = (const float*)d_in[16];
  const float* b2n    = (const float*)d_in[17];
  const float* offW1  = (const float*)d_in[18];
  const float* offb1  = (const float*)d_in[19];
  const float* offW2  = (const float*)d_in[20];
  const float* offb2  = (const float*)d_in[21];
  const float* dW1    = (const float*)d_in[22];
  const float* db1    = (const float*)d_in[23];
  const float* dW2    = (const float*)d_in[24];
  const float* db2    = (const float*)d_in[25];
  const float* sW1    = (const float*)d_in[26];
  const float* sb1    = (const float*)d_in[27];
  const float* sW2    = (const float*)d_in[28];
  const float* sb2    = (const float*)d_in[29];
  const float* pW1    = (const float*)d_in[30];
  const float* pb1    = (const float*)d_in[31];
  const float* pW2    = (const float*)d_in[32];
  const float* pb2    = (const float*)d_in[33];
  const float* ibp    = (const float*)d_in[34];
  const float* useful = (const float*)d_in[35];
  float* out = (float*)d_out;

  char* wsp = (char*)d_ws;
  size_t off = 0;
  auto alloc = [&](size_t bytes)->char*{
    char* p = wsp + off;
    off += (bytes + 255) & ~((size_t)255);
    return p;
  };
  int*   t_idx  = (int*)  alloc(BKQ*4);
  float* t_mask = (float*)alloc(BKQ*4);
  float* t_col  = (float*)alloc(BKQ*4);
  float* t_row  = (float*)alloc(BKQ*4);
  u16*   feat_bf= (u16*)  alloc((size_t)BB*TOK*CE*2);
  u16*   wtokT  = (u16*)  alloc((size_t)DD*CE*2);
  u16*   ctx_bf = (u16*)  alloc((size_t)BB*TOK*DD*2);
  u16*   ctxT_bf= (u16*)  alloc((size_t)BB*TOK*DD*2);
  float* x      = (float*)alloc((size_t)BKQ*DD*4);
  float* h      = (float*)alloc((size_t)BKQ*DD*4);
  float* u      = (float*)alloc((size_t)BKQ*DD*4);
  u16*   z_bf   = (u16*)  alloc((size_t)BKQ*HH*DD*2);
  float* logits = (float*)alloc((size_t)BB*QH*TOK*4);
  u16*   att_bf = (u16*)  alloc((size_t)BB*QH*TOK*2);
  float* cbuf   = (float*)alloc((size_t)BKQ*HH*DD*4);
  float* o_pre  = (float*)alloc((size_t)BKQ*DD*4);
  float* mid    = (float*)alloc((size_t)BKQ*MM*4);
  float* h_off  = (float*)alloc((size_t)BKQ*DD*4);
  float* h_d    = (float*)alloc((size_t)BKQ*DD*4);
  float* h_s    = (float*)alloc((size_t)BKQ*DD*4);
  float* h_p    = (float*)alloc((size_t)BKQ*DD*4);
  float* cvec   = (float*)alloc(DD*4);
  float* cvec2  = (float*)alloc(NJ*6*4);
  float* rot6d  = (float*)alloc((size_t)BKQ*NJ*6*4);
  if (off > ws_size) return;

  const float scale = 0.17677669529663687f; // 1/sqrt(32)

  k_nms_topk<<<BB, 256, 0, stream>>>(scores, t_idx, t_mask, t_col, t_row);
  k_cvt_bf16<<<3072, 256, 0, stream>>>(feat, feat_bf, BB*TOK*CE/4);
  k_tconv_f2b<<<dim3(DD/32, CE/32), 256, 0, stream>>>(Wtok, wtokT, CE, DD);
  // ctx = feat @ Wtok + btok + pos_emb   (bf16 out)
  k_gemm_bt<2><<<dim3(DD/128, (BB*TOK)/128, 1), 256, 0, stream>>>(
      feat_bf, wtokT, nullptr, ctx_bf, btok, pos_emb, CE, CE, CE, DD, 0, 0, 0, 1);
  k_transp_b<<<dim3(DD/32, TOK/32, BB), 256, 0, stream>>>(ctx_bf, ctxT_bf, TOK, DD);
  k_gather<<<BKQ, 256, 0, stream>>>(feat, Wtok, btok, pos_emb, t_idx, x);

  for (int l = 0; l < LL; l++){
    k_ln64<<<BKQ, 256, 0, stream>>>(x, g1 + l*DD, b1n + l*DD, h);
    // u = LN(x) @ Wq * scale
    k_smallmm<0,0><<<dim3(8,4,1), 256, 0, stream>>>(h, Wq + (size_t)l*DD*DD, nullptr, u, DD, DD, DD, DD, DD, scale);
    k_zker<<<dim3(4,HH), 256, 0, stream>>>(u, Wk + (size_t)l*DD*DD, z_bf);
    // logits[b] = Z_b (256x512) @ ctx_b^T (512x4096)
    k_gemm_bt<0><<<dim3(TOK/128, QH/128, BB), 256, 0, stream>>>(
        z_bf, ctx_bf, logits, nullptr, nullptr, nullptr,
        DD, DD, DD, TOK, (long)QH*DD, (long)TOK*DD, (long)QH*TOK, 1);
    k_softmax<<<BB*QH, 256, 0, stream>>>(logits, att_bf);
    hipMemsetAsync(cbuf, 0, (size_t)BKQ*HH*DD*4, stream);
    // c[b] = att_b (256x4096) @ ctxT_b^T (512x4096)^T, split-K=8, atomic accumulate
    k_gemm_bt<1><<<dim3(DD/128, QH/128, BB*8), 256, 0, stream>>>(
        att_bf, ctxT_bf, cbuf, nullptr, nullptr, nullptr,
        DD, TOK, TOK, DD, (long)QH*TOK, (long)DD*TOK, (long)QH*DD, 8);
    k_ovp<<<dim3(4,HH), 256, 0, stream>>>(cbuf, Wv + (size_t)l*DD*DD, o_pre);
    // x += o_pre @ Wo  (split-K=2, atomic)
    k_smallmm<0,2><<<dim3(8,4,2), 256, 0, stream>>>(o_pre, Wo + (size_t)l*DD*DD, nullptr, x, DD, DD, DD, DD, DD, 1.f);
    k_ln64<<<BKQ, 256, 0, stream>>>(x, g2 + l*DD, b2n + l*DD, h);
    // mid = gelu(h2 @ W1 + bf1)
    k_smallmm<2,0><<<dim3(32,4,1), 256, 0, stream>>>(h, W1 + (size_t)l*DD*MM, bf1 + l*MM, mid, MM, DD, DD, MM, MM, 1.f);
    // x += mid @ W2 + bf2  (split-K=4, atomic)
    k_smallmm<0,2><<<dim3(8,4,4), 256, 0, stream>>>(mid, W2 + (size_t)l*MM*DD, bf2 + l*DD, x, DD, MM, MM, DD, DD, 1.f);
  }

  k_smallmm<1,0><<<dim3(8,4,1), 256, 0, stream>>>(x, offW1, offb1, h_off, DD, DD, DD, DD, DD, 1.f);
  k_smallmm<1,0><<<dim3(8,4,1), 256, 0, stream>>>(x, dW1,   db1,   h_d,   DD, DD, DD, DD, DD, 1.f);
  k_smallmm<1,0><<<dim3(8,4,1), 256, 0, stream>>>(x, sW1,   sb1,   h_s,   DD, DD, DD, DD, DD, 1.f);
  k_cvec<<<2, 256, 0, stream>>>(pW1, pb1, ibp, cvec);
  k_smallmm<1,0><<<dim3(8,4,1), 256, 0, stream>>>(x, pW1, cvec, h_p, DD, DD, DD, DD, DD, 1.f);
  k_cvec2<<<4, 256, 0, stream>>>(pb2, ibp, cvec2);
  k_smallmm<0,0><<<dim3(16,4,1), 256, 0, stream>>>(h_p, pW2, cvec2, rot6d, NJ*6, DD, DD, NJ*6, NJ*6, 1.f);
  k_final<<<BKQ, 256, 0, stream>>>(h_off, h_d, h_s, rot6d, offW2, offb2, dW2, db2, sW2, sb2,
                                   K_cam, useful, t_mask, t_col, t_row, out);
}

// Round 2
// 2143.374 us; speedup vs baseline: 1.1064x; 1.1064x over previous
//
#include <hip/hip_runtime.h>

typedef unsigned int uint;
typedef unsigned short u16;

#define BB 4
#define CE 384
#define DD 512
#define LL 8
#define HH 16
#define MM 2048
#define NJ 163
#define TOK 4096
#define BKQ 64
#define QH 256
#define OUTW 1486

typedef __attribute__((ext_vector_type(8))) short short8;
typedef __attribute__((ext_vector_type(4))) float float4v;

static __device__ __forceinline__ u16 f2bf(float f){
  union { float f; uint u; } c; c.f = f;
  uint u = c.u;
  return (u16)((u + 0x7FFFu + ((u >> 16) & 1u)) >> 16);
}
static __device__ __forceinline__ float wred_sum(float v){
  for (int o = 32; o; o >>= 1) v += __shfl_xor(v, o, 64);
  return v;
}
static __device__ __forceinline__ float wred_max(float v){
  for (int o = 32; o; o >>= 1) v = fmaxf(v, __shfl_xor(v, o, 64));
  return v;
}

// ---------------- NMS + top-k (exact fp32, stable ties) ----------------
__global__ __launch_bounds__(256) void k_nms_topk(const float* __restrict__ scores,
    int* __restrict__ oidx, float* __restrict__ omask, float* __restrict__ ocol, float* __restrict__ orow)
{
  int b = blockIdx.x, t = threadIdx.x;
  __shared__ float sraw[4096];
  __shared__ float snms[4096];
  __shared__ float bv[256];
  __shared__ int   bi[256];
  const float* sp = scores + (size_t)b * 4096;
  for (int i = t; i < 4096; i += 256) sraw[i] = sp[i];
  __syncthreads();
  for (int i = t; i < 4096; i += 256){
    int r = i >> 6, c = i & 63;
    float mx = -1e30f;
    for (int dr = -1; dr <= 1; dr++){
      int rr = r + dr; if (rr < 0 || rr > 63) continue;
      for (int dc = -1; dc <= 1; dc++){
        int cc = c + dc; if (cc < 0 || cc > 63) continue;
        mx = fmaxf(mx, sraw[rr*64+cc]);
      }
    }
    snms[i] = (sraw[i] == mx) ? sraw[i] : 0.0f;
  }
  __syncthreads();
  for (int iter = 0; iter < 16; iter++){
    float best = -1e30f; int bidx = 1 << 30;
    for (int i = t; i < 4096; i += 256){
      float v = snms[i];
      if (v > best){ best = v; bidx = i; }
    }
    bv[t] = best; bi[t] = bidx;
    __syncthreads();
    for (int s = 128; s > 0; s >>= 1){
      if (t < s){
        if (bv[t+s] > bv[t] || (bv[t+s] == bv[t] && bi[t+s] < bi[t])){ bv[t] = bv[t+s]; bi[t] = bi[t+s]; }
      }
      __syncthreads();
    }
    if (t == 0){
      int idx = bi[0]; float val = bv[0];
      oidx[b*16+iter] = idx;
      omask[b*16+iter] = (val >= 0.3f) ? 1.f : 0.f;
      ocol[b*16+iter] = (float)(idx & 63);
      orow[b*16+iter] = (float)(idx >> 6);
      snms[idx] = -1e30f;
    }
    __syncthreads();
  }
}

// ---------------- fp32 -> bf16 convert ----------------
__global__ __launch_bounds__(256) void k_cvt_bf16(const float* __restrict__ in, u16* __restrict__ out, int n4){
  int i = blockIdx.x*256 + threadIdx.x;
  int stride = gridDim.x*256;
  for (int j = i; j < n4; j += stride){
    float4 v = ((const float4*)in)[j];
    ushort4 o;
    o.x = f2bf(v.x); o.y = f2bf(v.y); o.z = f2bf(v.z); o.w = f2bf(v.w);
    ((ushort4*)out)[j] = o;
  }
}

// ---------------- transpose+convert fp32(R,C) -> bf16(C,R) ----------------
__global__ __launch_bounds__(256) void k_tconv_f2b(const float* __restrict__ in, u16* __restrict__ out, int R, int C){
  __shared__ float tile[32][33];
  int c0 = blockIdx.x*32, r0 = blockIdx.y*32;
  int tx = threadIdx.x & 31, ty = threadIdx.x >> 5;
  for (int i = 0; i < 32; i += 8) tile[ty+i][tx] = in[(size_t)(r0+ty+i)*C + c0+tx];
  __syncthreads();
  for (int i = 0; i < 32; i += 8) out[(size_t)(c0+ty+i)*R + r0+tx] = f2bf(tile[tx][ty+i]);
}

// ---------------- bf16 transpose (R,C) -> (C,R), batched in z ----------------
__global__ __launch_bounds__(256) void k_transp_b(const u16* __restrict__ in, u16* __restrict__ out, int R, int C){
  in  += (size_t)blockIdx.z * R * C;
  out += (size_t)blockIdx.z * R * C;
  __shared__ u16 tile[32][33];
  int c0 = blockIdx.x*32, r0 = blockIdx.y*32;
  int tx = threadIdx.x & 31, ty = threadIdx.x >> 5;
  for (int i = 0; i < 32; i += 8) tile[ty+i][tx] = in[(size_t)(r0+ty+i)*C + c0+tx];
  __syncthreads();
  for (int i = 0; i < 32; i += 8) out[(size_t)(c0+ty+i)*R + r0+tx] = tile[tx][ty+i];
}

// ---------------- MFMA bf16 GEMM, C = A(MxK) * Bt(NxK)^T ----------------
// EPI 0: store f32   EPI 2: embed epilogue -> bf16   EPI 3: per-split partial store f32
template<int EPI>
__global__ __launch_bounds__(256) void k_gemm_bt(
    const u16* __restrict__ A, const u16* __restrict__ Bt,
    float* __restrict__ C, u16* __restrict__ Cb,
    const float* __restrict__ ep1, const float* __restrict__ ep2,
    int Kslice, int lda, int ldb, int ldc,
    long sA, long sB, long sC, int ksplit)
{
  int bz = blockIdx.z;
  int batch = bz / ksplit, ks = bz - batch*ksplit;
  const u16* Ab = A + (size_t)batch*sA + (size_t)ks*Kslice;
  const u16* Bb = Bt + (size_t)batch*sB + (size_t)ks*Kslice;
  int m0 = blockIdx.y*128, n0 = blockIdx.x*128;
  __shared__ __align__(16) u16 As[128*32];
  __shared__ __align__(16) u16 Bs[128*32];
  int t = threadIdx.x, lane = t & 63, wave = t >> 6;
  int wr = wave >> 1, wc = wave & 1;
  int lr = lane & 15, lk = lane >> 4;
  int srow = t >> 2, scol = (t & 3) * 8;
  float4v acc[4][4];
  float4v z4 = {0.f, 0.f, 0.f, 0.f};
  #pragma unroll
  for (int i = 0; i < 4; i++)
    #pragma unroll
    for (int j = 0; j < 4; j++) acc[i][j] = z4;

  for (int kt = 0; kt < Kslice; kt += 32){
    int4 a0 = *(const int4*)(Ab + (size_t)(m0+srow)*lda + kt + scol);
    int4 a1 = *(const int4*)(Ab + (size_t)(m0+64+srow)*lda + kt + scol);
    int4 b0 = *(const int4*)(Bb + (size_t)(n0+srow)*ldb + kt + scol);
    int4 b1 = *(const int4*)(Bb + (size_t)(n0+64+srow)*ldb + kt + scol);
    __syncthreads();
    *(int4*)&As[srow*32 + scol] = a0;
    *(int4*)&As[(64+srow)*32 + scol] = a1;
    *(int4*)&Bs[srow*32 + scol] = b0;
    *(int4*)&Bs[(64+srow)*32 + scol] = b1;
    __syncthreads();
    short8 af[4], bf[4];
    #pragma unroll
    for (int i = 0; i < 4; i++) af[i] = *(const short8*)&As[(wr*64 + i*16 + lr)*32 + lk*8];
    #pragma unroll
    for (int j = 0; j < 4; j++) bf[j] = *(const short8*)&Bs[(wc*64 + j*16 + lr)*32 + lk*8];
    #pragma unroll
    for (int i = 0; i < 4; i++)
      #pragma unroll
      for (int j = 0; j < 4; j++)
        acc[i][j] = __builtin_amdgcn_mfma_f32_16x16x32_bf16(af[i], bf[j], acc[i][j], 0, 0, 0);
  }
  size_t cbase = (size_t)(EPI == 3 ? bz : batch) * sC;
  #pragma unroll
  for (int i = 0; i < 4; i++){
    int rbase = m0 + wr*64 + i*16 + lk*4;
    #pragma unroll
    for (int j = 0; j < 4; j++){
      int cc = n0 + wc*64 + j*16 + lr;
      #pragma unroll
      for (int jj = 0; jj < 4; jj++){
        float v = acc[i][j][jj];
        int rr = rbase + jj;
        if (EPI == 0 || EPI == 3) C[cbase + (size_t)rr*ldc + cc] = v;
        else {
          float vv = v + ep1[cc] + ep2[(size_t)(rr & 4095)*DD + cc];
          Cb[(size_t)rr*ldc + cc] = f2bf(vv);
        }
      }
    }
  }
}

// ---------------- gather + fp32 embed for the 64 selected tokens ----------------
__global__ __launch_bounds__(256) void k_gather(const float* __restrict__ feat, const float* __restrict__ Wtok,
    const float* __restrict__ btok, const float* __restrict__ pos_emb, const int* __restrict__ oidx,
    float* __restrict__ x)
{
  int bq = blockIdx.x, b = bq >> 4;
  int tok = oidx[bq];
  __shared__ float fs[CE];
  const float* fr = feat + ((size_t)b*TOK + tok) * CE;
  for (int i = threadIdx.x; i < CE; i += 256) fs[i] = fr[i];
  __syncthreads();
  for (int d = threadIdx.x; d < DD; d += 256){
    float acc = btok[d] + pos_emb[(size_t)tok*DD + d];
    for (int i = 0; i < CE; i++) acc += fs[i] * Wtok[(size_t)i*DD + d];
    x[(size_t)bq*DD + d] = acc;
  }
}

// ---------------- fused LayerNorm + small GEMM (M=16 rows/block, K=512) ----------------
// C[m0+r][col] = ACT( (LN(x[m0+r]) @ Bm)[col]*alpha + bias[col] )
template<int ACT>
__global__ __launch_bounds__(256) void k_lnmm(
    const float* __restrict__ x, const float* __restrict__ g, const float* __restrict__ bb,
    const float* __restrict__ Bm, const float* __restrict__ bias, float* __restrict__ C,
    int N, int ldb, int ldc, float alpha)
{
  __shared__ float As[16*520];
  int t = threadIdx.x;
  int m0 = blockIdx.y * 16;
  int w = t >> 6, ln = t & 63;
  // stage 16 full rows of x
  for (int idx = t; idx < 2048; idx += 256){
    int r = idx >> 7, c4 = (idx & 127) * 4;
    float4 v = *(const float4*)&x[(size_t)(m0+r)*DD + c4];
    As[r*520 + c4+0] = v.x; As[r*520 + c4+1] = v.y;
    As[r*520 + c4+2] = v.z; As[r*520 + c4+3] = v.w;
  }
  __syncthreads();
  // each wave normalizes 4 rows
  #pragma unroll
  for (int rr = 0; rr < 4; rr++){
    int row = w*4 + rr;
    float s = 0.f;
    #pragma unroll
    for (int j = 0; j < 8; j++) s += As[row*520 + ln + j*64];
    s = wred_sum(s);
    float mu = s * (1.f/DD);
    float q = 0.f;
    #pragma unroll
    for (int j = 0; j < 8; j++){ float d = As[row*520 + ln + j*64] - mu; q += d*d; }
    q = wred_sum(q);
    float inv = rsqrtf(q * (1.f/DD) + 1e-5f);
    #pragma unroll
    for (int j = 0; j < 8; j++){
      int k = ln + j*64;
      As[row*520 + k] = (As[row*520 + k] - mu)*inv*g[k] + bb[k];
    }
  }
  __syncthreads();
  int col = blockIdx.x * 64 + ln;
  float acc[4] = {0.f, 0.f, 0.f, 0.f};
  #pragma unroll 4
  for (int k = 0; k < DD; k++){
    float bv = Bm[(size_t)k*ldb + col];
    acc[0] += As[(w*4+0)*520 + k] * bv;
    acc[1] += As[(w*4+1)*520 + k] * bv;
    acc[2] += As[(w*4+2)*520 + k] * bv;
    acc[3] += As[(w*4+3)*520 + k] * bv;
  }
  float bsv = bias ? bias[col] : 0.f;
  #pragma unroll
  for (int i = 0; i < 4; i++){
    float v = acc[i]*alpha + bsv;
    if (ACT == 2) v = 0.5f*v*(1.f + tanhf(0.7978845608028654f*(v + 0.044715f*v*v*v)));
    C[(size_t)(m0 + w*4 + i)*ldc + col] = v;
  }
}

// ---------------- small fp32 GEMM: C(MxN) = A(MxK) @ B(KxN) ----------------
// ACT 0 none / 1 relu.  RES 0 store / 2 atomicAdd (split-K via grid.z)
template<int ACT, int RES>
__global__ __launch_bounds__(256) void k_smallmm(
    const float* __restrict__ A, const float* __restrict__ Bm,
    const float* __restrict__ bias, float* __restrict__ C,
    int N, int K, int lda, int ldb, int ldc, float alpha)
{
  __shared__ float As[16*256];
  int t = threadIdx.x;
  int m0 = blockIdx.y * 16;
  int col = blockIdx.x * 64 + (t & 63);
  int w = t >> 6;
  int kper = K / gridDim.z;
  int kbeg = blockIdx.z * kper;
  float acc[4] = {0.f, 0.f, 0.f, 0.f};
  for (int kc = kbeg; kc < kbeg + kper; kc += 256){
    __syncthreads();
    for (int idx = t; idx < 4096; idx += 256){
      int r = idx >> 8, k = idx & 255;
      As[idx] = A[(size_t)(m0+r)*lda + kc + k];
    }
    __syncthreads();
    if (col < N){
      #pragma unroll 4
      for (int k = 0; k < 256; k++){
        float bv = Bm[(size_t)(kc+k)*ldb + col];
        acc[0] += As[(w*4+0)*256 + k] * bv;
        acc[1] += As[(w*4+1)*256 + k] * bv;
        acc[2] += As[(w*4+2)*256 + k] * bv;
        acc[3] += As[(w*4+3)*256 + k] * bv;
      }
    }
  }
  if (col < N){
    float bsv = (bias && blockIdx.z == 0) ? bias[col] : 0.f;
    #pragma unroll
    for (int i = 0; i < 4; i++){
      float v = acc[i]*alpha + bsv;
      if (ACT == 1) v = fmaxf(v, 0.f);
      size_t o = (size_t)(m0 + w*4 + i)*ldc + col;
      if (RES == 0) C[o] = v;
      else atomicAdd(&C[o], v);
    }
  }
}

// ---------------- 4 head GEMMs in one dispatch (relu, N=K=512) ----------------
__global__ __launch_bounds__(256) void k_heads4(const float* __restrict__ x,
    const float* __restrict__ offW1, const float* __restrict__ offb1,
    const float* __restrict__ dW1, const float* __restrict__ db1,
    const float* __restrict__ sW1, const float* __restrict__ sb1,
    const float* __restrict__ pW1, const float* __restrict__ cvec,
    float* __restrict__ h_off, float* __restrict__ h_d, float* __restrict__ h_s, float* __restrict__ h_p)
{
  const float* Bm; const float* bias; float* C;
  int z = blockIdx.z;
  if (z == 0){ Bm = offW1; bias = offb1; C = h_off; }
  else if (z == 1){ Bm = dW1; bias = db1; C = h_d; }
  else if (z == 2){ Bm = sW1; bias = sb1; C = h_s; }
  else { Bm = pW1; bias = cvec; C = h_p; }
  __shared__ float As[16*256];
  int t = threadIdx.x;
  int m0 = blockIdx.y * 16;
  int col = blockIdx.x * 64 + (t & 63);
  int w = t >> 6;
  float acc[4] = {0.f, 0.f, 0.f, 0.f};
  for (int kc = 0; kc < DD; kc += 256){
    __syncthreads();
    for (int idx = t; idx < 4096; idx += 256){
      int r = idx >> 8, k = idx & 255;
      As[idx] = x[(size_t)(m0+r)*DD + kc + k];
    }
    __syncthreads();
    #pragma unroll 4
    for (int k = 0; k < 256; k++){
      float bv = Bm[(size_t)(kc+k)*DD + col];
      acc[0] += As[(w*4+0)*256 + k] * bv;
      acc[1] += As[(w*4+1)*256 + k] * bv;
      acc[2] += As[(w*4+2)*256 + k] * bv;
      acc[3] += As[(w*4+3)*256 + k] * bv;
    }
  }
  float bsv = bias[col];
  #pragma unroll
  for (int i = 0; i < 4; i++){
    float v = fmaxf(acc[i] + bsv, 0.f);
    C[(size_t)(m0 + w*4 + i)*DD + col] = v;
  }
}

// ---------------- z[bq][h][d] = sum_dh u[bq][h*32+dh] * Wk[d][h*32+dh]  (bf16 out) ----------------
__global__ __launch_bounds__(256) void k_zker(const float* __restrict__ u, const float* __restrict__ Wk, u16* __restrict__ z){
  int ds = blockIdx.x, h = blockIdx.y, t = threadIdx.x;
  __shared__ float us[64*33];
  __shared__ float wks[128*33];
  for (int idx = t; idx < 2048; idx += 256){ int bq = idx >> 5, dh = idx & 31; us[bq*33+dh] = u[(size_t)bq*DD + h*32 + dh]; }
  for (int idx = t; idx < 4096; idx += 256){ int r = idx >> 5, dh = idx & 31; wks[r*33+dh] = Wk[(size_t)(ds*128+r)*DD + h*32 + dh]; }
  __syncthreads();
  for (int oi = t; oi < 8192; oi += 256){
    int d = oi & 127, bq = oi >> 7;
    float acc = 0.f;
    #pragma unroll
    for (int dh = 0; dh < 32; dh++) acc += us[bq*33+dh] * wks[d*33+dh];
    z[((size_t)bq*HH + h)*DD + ds*128 + d] = f2bf(acc);
  }
}

// ---------------- softmax over 4096, fp32 in -> bf16 probs ----------------
__global__ __launch_bounds__(256) void k_softmax(const float* __restrict__ lg, u16* __restrict__ att){
  int row = blockIdx.x, t = threadIdx.x;
  const float* p = lg + (size_t)row*TOK;
  float v[16]; float mx = -1e30f;
  #pragma unroll
  for (int i = 0; i < 16; i++){ v[i] = p[t + i*256]; mx = fmaxf(mx, v[i]); }
  mx = wred_max(mx);
  __shared__ float sm[4]; __shared__ float ssum[4];
  if ((t & 63) == 0) sm[t >> 6] = mx;
  __syncthreads();
  mx = fmaxf(fmaxf(sm[0], sm[1]), fmaxf(sm[2], sm[3]));
  float s = 0.f;
  #pragma unroll
  for (int i = 0; i < 16; i++){ v[i] = expf(v[i] - mx); s += v[i]; }
  s = wred_sum(s);
  if ((t & 63) == 0) ssum[t >> 6] = s;
  __syncthreads();
  s = ssum[0]+ssum[1]+ssum[2]+ssum[3];
  float inv = 1.f / s;
  u16* q = att + (size_t)row*TOK;
  #pragma unroll
  for (int i = 0; i < 16; i++) q[t + i*256] = f2bf(v[i]*inv);
}

// ---------------- o_pre[bq][h*32+dh] = sum_D (Σ_s P)[bq][h][D] * Wv[D][h*32+dh] ----------------
__global__ __launch_bounds__(256) void k_ovp(const float* __restrict__ P, const float* __restrict__ Wv, float* __restrict__ op){
  int bg = blockIdx.x, h = blockIdx.y, t = threadIdx.x;
  __shared__ float wvs[128*33];
  __shared__ float cs[16*129];
  int dh = t & 31, bl = t >> 5;
  float acc0 = 0.f, acc1 = 0.f;
  for (int Dc = 0; Dc < DD; Dc += 128){
    __syncthreads();
    for (int idx = t; idx < 4096; idx += 256){ int r = idx >> 5, q = idx & 31; wvs[r*33+q] = Wv[(size_t)(Dc+r)*DD + h*32 + q]; }
    for (int idx = t; idx < 2048; idx += 256){
      int r = idx >> 7, k = idx & 127;
      size_t base = ((size_t)(bg*8))*((size_t)QH*DD) + (size_t)(r*16+h)*DD + Dc + k;
      float s = 0.f;
      #pragma unroll
      for (int sp = 0; sp < 8; sp++) s += P[base + (size_t)sp*((size_t)QH*DD)];
      cs[r*129+k] = s;
    }
    __syncthreads();
    #pragma unroll 4
    for (int k = 0; k < 128; k++){
      float wv = wvs[k*33+dh];
      acc0 += cs[bl*129 + k] * wv;
      acc1 += cs[(bl+8)*129 + k] * wv;
    }
  }
  op[(size_t)(bg*16+bl)*DD + h*32 + dh] = acc0;
  op[(size_t)(bg*16+bl+8)*DD + h*32 + dh] = acc1;
}

// ---------------- constants for pose head (wave per output d) ----------------
__global__ __launch_bounds__(256) void k_cvec(const float* __restrict__ pW1, const float* __restrict__ pb1,
    const float* __restrict__ ibp, float* __restrict__ cvec)
{
  int d = blockIdx.x*4 + (threadIdx.x >> 6);
  int ln = threadIdx.x & 63;
  float acc = 0.f;
  for (int i = ln; i < NJ*6; i += 64) acc += ibp[i] * pW1[(size_t)(DD+i)*DD + d];
  acc = wred_sum(acc);
  if (ln == 0) cvec[d] = acc + pb1[d];
}
__global__ __launch_bounds__(256) void k_cvec2(const float* __restrict__ pb2, const float* __restrict__ ibp, float* __restrict__ cv){
  int j = blockIdx.x*256 + threadIdx.x;
  if (j < NJ*6) cv[j] = pb2[j] + ibp[j];
}

// ---------------- final heads + Gram-Schmidt + assembly ----------------
__global__ __launch_bounds__(256) void k_final(
    const float* __restrict__ h_off, const float* __restrict__ h_d, const float* __restrict__ h_s,
    const float* __restrict__ rot6d,
    const float* __restrict__ offW2, const float* __restrict__ offb2,
    const float* __restrict__ dW2, const float* __restrict__ db2,
    const float* __restrict__ sW2, const float* __restrict__ sb2,
    const float* __restrict__ K_cam, const float* __restrict__ useful,
    const float* __restrict__ maskf, const float* __restrict__ colf, const float* __restrict__ rowf,
    float* __restrict__ out)
{
  int bq = blockIdx.x, t = threadIdx.x, b = bq >> 4;
  float po0 = 0.f, po1 = 0.f, pd = 0.f, ps[11];
  #pragma unroll
  for (int j = 0; j < 11; j++) ps[j] = 0.f;
  for (int i = t; i < DD; i += 256){
    float ho = h_off[(size_t)bq*DD + i];
    float hd = h_d[(size_t)bq*DD + i];
    float hs = h_s[(size_t)bq*DD + i];
    po0 += ho*offW2[i*2]; po1 += ho*offW2[i*2+1];
    pd += hd*dW2[i];
    #pragma unroll
    for (int j = 0; j < 11; j++) ps[j] += hs*sW2[i*11+j];
  }
  __shared__ float sred[4][14];
  __shared__ float sout[14];
  int wv = t >> 6, ln = t & 63;
  float vals[14];
  vals[0] = po0; vals[1] = po1; vals[2] = pd;
  #pragma unroll
  for (int j = 0; j < 11; j++) vals[3+j] = ps[j];
  #pragma unroll
  for (int kk = 0; kk < 14; kk++){
    float r = wred_sum(vals[kk]);
    if (ln == 0) sred[wv][kk] = r;
  }
  __syncthreads();
  if (t < 14) sout[t] = sred[0][t]+sred[1][t]+sred[2][t]+sred[3][t];
  __syncthreads();
  float m = maskf[bq];
  if (t == 0){
    float off0 = sout[0] + offb2[0], off1 = sout[1] + offb2[1];
    float draw = sout[2] + db2[0];
    float l0 = (colf[bq] + 0.5f + off0) * 14.0f;
    float l1 = (rowf[bq] + 0.5f + off1) * 14.0f;
    float fx = K_cam[b*9+0], cx = K_cam[b*9+2], fy = K_cam[b*9+4], cy = K_cam[b*9+5];
    float dist = fx / fmaxf(expf(draw), 1e-5f);
    float tx = (l0 - cx) / fx * dist, ty = (l1 - cy) / fy * dist;
    float* o = out + (size_t)bq*OUTW;
    o[0] = l0*m; o[1] = l1*m; o[2] = off0*m; o[3] = off1*m; o[4] = dist*m;
    o[5] = tx*m; o[6] = ty*m; o[7] = dist*m;
    #pragma unroll
    for (int j = 0; j < 11; j++){ float sp = sout[3+j] + sb2[j]; o[8+j] = m / (1.f + expf(-sp)); }
  }
  if (t < NJ){
    const float* rp = rot6d + (size_t)bq*(NJ*6) + t*6;
    float a0 = rp[0], b0 = rp[1], a1 = rp[2], b1 = rp[3], a2 = rp[4], b2 = rp[5];
    float n0 = sqrtf(a0*a0 + a1*a1 + a2*a2);
    float i0 = 1.f / (n0 + 1e-8f);
    float u00 = a0*i0, u01 = a1*i0, u02 = a2*i0;
    float dt = b0*u00 + b1*u01 + b2*u02;
    float v0 = b0 - dt*u00, v1 = b1 - dt*u01, v2 = b2 - dt*u02;
    float n1 = sqrtf(v0*v0 + v1*v1 + v2*v2);
    float i1 = 1.f / (n1 + 1e-8f);
    float u10 = v0*i1, u11 = v1*i1, u12 = v2*i1;
    float u20 = u01*u12 - u02*u11;
    float u21 = u02*u10 - u00*u12;
    float u22 = u00*u11 - u01*u10;
    float um = useful[t], om = 1.f - um;
    float R00 = um*u00 + om, R01 = um*u10,      R02 = um*u20;
    float R10 = um*u01,      R11 = um*u11 + om, R12 = um*u21;
    float R20 = um*u02,      R21 = um*u12,      R22 = um*u22 + om;
    float* o = out + (size_t)bq*OUTW + 19 + t*9;
    o[0] = R00*m; o[1] = R01*m; o[2] = R02*m;
    o[3] = R10*m; o[4] = R11*m; o[5] = R12*m;
    o[6] = R20*m; o[7] = R21*m; o[8] = R22*m;
  }
}

extern "C" void kernel_launch(void* const* d_in, const int* in_sizes, int n_in,
                              void* d_out, int out_size, void* d_ws, size_t ws_size,
                              hipStream_t stream)
{
  const float* feat   = (const float*)d_in[0];
  const float* scores = (const float*)d_in[1];
  const float* K_cam  = (const float*)d_in[2];
  const float* pos_emb= (const float*)d_in[3];
  const float* Wtok   = (const float*)d_in[4];
  const float* btok   = (const float*)d_in[5];
  const float* Wq     = (const float*)d_in[6];
  const float* Wk     = (const float*)d_in[7];
  const float* Wv     = (const float*)d_in[8];
  const float* Wo     = (const float*)d_in[9];
  const float* g1     = (const float*)d_in[10];
  const float* b1n    = (const float*)d_in[11];
  const float* W1     = (const float*)d_in[12];
  const float* bf1    = (const float*)d_in[13];
  const float* W2     = (const float*)d_in[14];
  const float* bf2    = (const float*)d_in[15];
  const float* g2     = (const float*)d_in[16];
  const float* b2n    = (const float*)d_in[17];
  const float* offW1  = (const float*)d_in[18];
  const float* offb1  = (const float*)d_in[19];
  const float* offW2  = (const float*)d_in[20];
  const float* offb2  = (const float*)d_in[21];
  const float* dW1    = (const float*)d_in[22];
  const float* db1    = (const float*)d_in[23];
  const float* dW2    = (const float*)d_in[24];
  const float* db2    = (const float*)d_in[25];
  const float* sW1    = (const float*)d_in[26];
  const float* sb1    = (const float*)d_in[27];
  const float* sW2    = (const float*)d_in[28];
  const float* sb2    = (const float*)d_in[29];
  const float* pW1    = (const float*)d_in[30];
  const float* pb1    = (const float*)d_in[31];
  const float* pW2    = (const float*)d_in[32];
  const float* pb2    = (const float*)d_in[33];
  const float* ibp    = (const float*)d_in[34];
  const float* useful = (const float*)d_in[35];
  float* out = (float*)d_out;

  char* wsp = (char*)d_ws;
  size_t off = 0;
  auto alloc = [&](size_t bytes)->char*{
    char* p = wsp + off;
    off += (bytes + 255) & ~((size_t)255);
    return p;
  };
  int*   t_idx  = (int*)  alloc(BKQ*4);
  float* t_mask = (float*)alloc(BKQ*4);
  float* t_col  = (float*)alloc(BKQ*4);
  float* t_row  = (float*)alloc(BKQ*4);
  u16*   feat_bf= (u16*)  alloc((size_t)BB*TOK*CE*2);
  u16*   wtokT  = (u16*)  alloc((size_t)DD*CE*2);
  u16*   ctx_bf = (u16*)  alloc((size_t)BB*TOK*DD*2);
  u16*   ctxT_bf= (u16*)  alloc((size_t)BB*TOK*DD*2);
  float* x      = (float*)alloc((size_t)BKQ*DD*4);
  float* u      = (float*)alloc((size_t)BKQ*DD*4);
  u16*   z_bf   = (u16*)  alloc((size_t)BKQ*HH*DD*2);
  float* logits = (float*)alloc((size_t)BB*QH*TOK*4);   // reused as att@V partials after softmax
  u16*   att_bf = (u16*)  alloc((size_t)BB*QH*TOK*2);
  float* o_pre  = (float*)alloc((size_t)BKQ*DD*4);
  float* mid    = (float*)alloc((size_t)BKQ*MM*4);
  float* h_off  = (float*)alloc((size_t)BKQ*DD*4);
  float* h_d    = (float*)alloc((size_t)BKQ*DD*4);
  float* h_s    = (float*)alloc((size_t)BKQ*DD*4);
  float* h_p    = (float*)alloc((size_t)BKQ*DD*4);
  float* cvec   = (float*)alloc(DD*4);
  float* cvec2  = (float*)alloc(NJ*6*4);
  float* rot6d  = (float*)alloc((size_t)BKQ*NJ*6*4);
  if (off > ws_size) return;

  const float scale = 0.17677669529663687f; // 1/sqrt(32)

  k_nms_topk<<<BB, 256, 0, stream>>>(scores, t_idx, t_mask, t_col, t_row);
  k_cvt_bf16<<<3072, 256, 0, stream>>>(feat, feat_bf, BB*TOK*CE/4);
  k_tconv_f2b<<<dim3(DD/32, CE/32), 256, 0, stream>>>(Wtok, wtokT, CE, DD);
  // ctx = feat @ Wtok + btok + pos_emb   (bf16 out)
  k_gemm_bt<2><<<dim3(DD/128, (BB*TOK)/128, 1), 256, 0, stream>>>(
      feat_bf, wtokT, nullptr, ctx_bf, btok, pos_emb, CE, CE, CE, DD, 0, 0, 0, 1);
  k_transp_b<<<dim3(DD/32, TOK/32, BB), 256, 0, stream>>>(ctx_bf, ctxT_bf, TOK, DD);
  k_gather<<<BKQ, 256, 0, stream>>>(feat, Wtok, btok, pos_emb, t_idx, x);

  for (int l = 0; l < LL; l++){
    // u = LN(x) @ Wq * scale   (fused LN)
    k_lnmm<0><<<dim3(8,4,1), 256, 0, stream>>>(x, g1 + l*DD, b1n + l*DD,
        Wq + (size_t)l*DD*DD, nullptr, u, DD, DD, DD, scale);
    k_zker<<<dim3(4,HH), 256, 0, stream>>>(u, Wk + (size_t)l*DD*DD, z_bf);
    // logits[b] = Z_b (256x512) @ ctx_b^T
    k_gemm_bt<0><<<dim3(TOK/128, QH/128, BB), 256, 0, stream>>>(
        z_bf, ctx_bf, logits, nullptr, nullptr, nullptr,
        DD, DD, DD, TOK, (long)QH*DD, (long)TOK*DD, (long)QH*TOK, 1);
    k_softmax<<<BB*QH, 256, 0, stream>>>(logits, att_bf);
    // partials[b*8+s] = att_b @ ctxT_b^T over K-slice s  (reuses logits buffer)
    k_gemm_bt<3><<<dim3(DD/128, QH/128, BB*8), 256, 0, stream>>>(
        att_bf, ctxT_bf, logits, nullptr, nullptr, nullptr,
        TOK/8, TOK, TOK, DD, (long)QH*TOK, (long)DD*TOK, (long)QH*DD, 8);
    k_ovp<<<dim3(4,HH), 256, 0, stream>>>(logits, Wv + (size_t)l*DD*DD, o_pre);
    // x += o_pre @ Wo  (split-K=2, atomic)
    k_smallmm<0,2><<<dim3(8,4,2), 256, 0, stream>>>(o_pre, Wo + (size_t)l*DD*DD, nullptr, x, DD, DD, DD, DD, DD, 1.f);
    // mid = gelu(LN2(x) @ W1 + bf1)   (fused LN)
    k_lnmm<2><<<dim3(32,4,1), 256, 0, stream>>>(x, g2 + l*DD, b2n + l*DD,
        W1 + (size_t)l*DD*MM, bf1 + l*MM, mid, MM, MM, MM, 1.f);
    // x += mid @ W2 + bf2  (split-K=4, atomic)
    k_smallmm<0,2><<<dim3(8,4,4), 256, 0, stream>>>(mid, W2 + (size_t)l*MM*DD, bf2 + l*DD, x, DD, MM, MM, DD, DD, 1.f);
  }

  k_cvec<<<DD/4, 256, 0, stream>>>(pW1, pb1, ibp, cvec);
  k_heads4<<<dim3(8,4,4), 256, 0, stream>>>(x, offW1, offb1, dW1, db1, sW1, sb1, pW1, cvec,
                                            h_off, h_d, h_s, h_p);
  k_cvec2<<<4, 256, 0, stream>>>(pb2, ibp, cvec2);
  k_smallmm<0,0><<<dim3(16,4,1), 256, 0, stream>>>(h_p, pW2, cvec2, rot6d, NJ*6, DD, DD, NJ*6, NJ*6, 1.f);
  k_final<<<BKQ, 256, 0, stream>>>(h_off, h_d, h_s, rot6d, offW2, offb2, dW2, db2, sW2, sb2,
                                   K_cam, useful, t_mask, t_col, t_row, out);
}

// Round 3
// 1304.985 us; speedup vs baseline: 1.8173x; 1.6425x over previous
//
#include <hip/hip_runtime.h>

typedef unsigned int uint;
typedef unsigned short u16;

#define BB 4
#define CE 384
#define DD 512
#define LL 8
#define HH 16
#define MM 2048
#define NJ 163
#define TOK 4096
#define BKQ 64
#define QH 256
#define OUTW 1486

typedef __attribute__((ext_vector_type(8))) short short8;
typedef __attribute__((ext_vector_type(4))) float float4v;

static __device__ __forceinline__ u16 f2bf(float f){
  union { float f; uint u; } c; c.f = f;
  uint u = c.u;
  return (u16)((u + 0x7FFFu + ((u >> 16) & 1u)) >> 16);
}
static __device__ __forceinline__ float wred_sum(float v){
  for (int o = 32; o; o >>= 1) v += __shfl_xor(v, o, 64);
  return v;
}
static __device__ __forceinline__ float wred_max(float v){
  for (int o = 32; o; o >>= 1) v = fmaxf(v, __shfl_xor(v, o, 64));
  return v;
}

// ---------------- NMS + top-k (exact fp32, stable ties) ----------------
__global__ __launch_bounds__(256) void k_nms_topk(const float* __restrict__ scores,
    int* __restrict__ oidx, float* __restrict__ omask, float* __restrict__ ocol, float* __restrict__ orow)
{
  int b = blockIdx.x, t = threadIdx.x;
  __shared__ float sraw[4096];
  __shared__ float snms[4096];
  __shared__ float bv[256];
  __shared__ int   bi[256];
  const float* sp = scores + (size_t)b * 4096;
  for (int i = t; i < 4096; i += 256) sraw[i] = sp[i];
  __syncthreads();
  for (int i = t; i < 4096; i += 256){
    int r = i >> 6, c = i & 63;
    float mx = -1e30f;
    for (int dr = -1; dr <= 1; dr++){
      int rr = r + dr; if (rr < 0 || rr > 63) continue;
      for (int dc = -1; dc <= 1; dc++){
        int cc = c + dc; if (cc < 0 || cc > 63) continue;
        mx = fmaxf(mx, sraw[rr*64+cc]);
      }
    }
    snms[i] = (sraw[i] == mx) ? sraw[i] : 0.0f;
  }
  __syncthreads();
  for (int iter = 0; iter < 16; iter++){
    float best = -1e30f; int bidx = 1 << 30;
    for (int i = t; i < 4096; i += 256){
      float v = snms[i];
      if (v > best){ best = v; bidx = i; }
    }
    bv[t] = best; bi[t] = bidx;
    __syncthreads();
    for (int s = 128; s > 0; s >>= 1){
      if (t < s){
        if (bv[t+s] > bv[t] || (bv[t+s] == bv[t] && bi[t+s] < bi[t])){ bv[t] = bv[t+s]; bi[t] = bi[t+s]; }
      }
      __syncthreads();
    }
    if (t == 0){
      int idx = bi[0]; float val = bv[0];
      oidx[b*16+iter] = idx;
      omask[b*16+iter] = (val >= 0.3f) ? 1.f : 0.f;
      ocol[b*16+iter] = (float)(idx & 63);
      orow[b*16+iter] = (float)(idx >> 6);
      snms[idx] = -1e30f;
    }
    __syncthreads();
  }
}

// ---------------- fp32 -> bf16 convert ----------------
__global__ __launch_bounds__(256) void k_cvt_bf16(const float* __restrict__ in, u16* __restrict__ out, int n4){
  int i = blockIdx.x*256 + threadIdx.x;
  int stride = gridDim.x*256;
  for (int j = i; j < n4; j += stride){
    float4 v = ((const float4*)in)[j];
    ushort4 o;
    o.x = f2bf(v.x); o.y = f2bf(v.y); o.z = f2bf(v.z); o.w = f2bf(v.w);
    ((ushort4*)out)[j] = o;
  }
}

// ---------------- transpose+convert fp32(R,C) -> bf16(C,R) ----------------
__global__ __launch_bounds__(256) void k_tconv_f2b(const float* __restrict__ in, u16* __restrict__ out, int R, int C){
  __shared__ float tile[32][33];
  int c0 = blockIdx.x*32, r0 = blockIdx.y*32;
  int tx = threadIdx.x & 31, ty = threadIdx.x >> 5;
  for (int i = 0; i < 32; i += 8) tile[ty+i][tx] = in[(size_t)(r0+ty+i)*C + c0+tx];
  __syncthreads();
  for (int i = 0; i < 32; i += 8) out[(size_t)(c0+ty+i)*R + r0+tx] = f2bf(tile[tx][ty+i]);
}

// ---------------- batched (per-layer z) transpose+convert fp32(R,C)->bf16(C,R) ----------------
__global__ __launch_bounds__(256) void k_tconvL(const float* __restrict__ in, u16* __restrict__ out, int R, int C){
  in  += (size_t)blockIdx.z * R * C;
  out += (size_t)blockIdx.z * R * C;
  __shared__ float tile[32][33];
  int c0 = blockIdx.x*32, r0 = blockIdx.y*32;
  int tx = threadIdx.x & 31, ty = threadIdx.x >> 5;
  for (int i = 0; i < 32; i += 8) tile[ty+i][tx] = in[(size_t)(r0+ty+i)*C + c0+tx];
  __syncthreads();
  for (int i = 0; i < 32; i += 8) out[(size_t)(c0+ty+i)*R + r0+tx] = f2bf(tile[tx][ty+i]);
}

// ---------------- bf16 transpose (R,C) -> (C,R), batched in z ----------------
__global__ __launch_bounds__(256) void k_transp_b(const u16* __restrict__ in, u16* __restrict__ out, int R, int C){
  in  += (size_t)blockIdx.z * R * C;
  out += (size_t)blockIdx.z * R * C;
  __shared__ u16 tile[32][33];
  int c0 = blockIdx.x*32, r0 = blockIdx.y*32;
  int tx = threadIdx.x & 31, ty = threadIdx.x >> 5;
  for (int i = 0; i < 32; i += 8) tile[ty+i][tx] = in[(size_t)(r0+ty+i)*C + c0+tx];
  __syncthreads();
  for (int i = 0; i < 32; i += 8) out[(size_t)(c0+ty+i)*R + r0+tx] = tile[tx][ty+i];
}

// ---------------- MFMA bf16 GEMM, C = A(MxK) * Bt(NxK)^T ----------------
// EPI 0: store f32   EPI 2: embed epilogue -> bf16   EPI 3: per-split partial store f32
template<int EPI>
__global__ __launch_bounds__(256) void k_gemm_bt(
    const u16* __restrict__ A, const u16* __restrict__ Bt,
    float* __restrict__ C, u16* __restrict__ Cb,
    const float* __restrict__ ep1, const float* __restrict__ ep2,
    int Kslice, int lda, int ldb, int ldc,
    long sA, long sB, long sC, int ksplit)
{
  int bz = blockIdx.z;
  int batch = bz / ksplit, ks = bz - batch*ksplit;
  const u16* Ab = A + (size_t)batch*sA + (size_t)ks*Kslice;
  const u16* Bb = Bt + (size_t)batch*sB + (size_t)ks*Kslice;
  int m0 = blockIdx.y*128, n0 = blockIdx.x*128;
  __shared__ __align__(16) u16 As[128*32];
  __shared__ __align__(16) u16 Bs[128*32];
  int t = threadIdx.x, lane = t & 63, wave = t >> 6;
  int wr = wave >> 1, wc = wave & 1;
  int lr = lane & 15, lk = lane >> 4;
  int srow = t >> 2, scol = (t & 3) * 8;
  float4v acc[4][4];
  float4v z4 = {0.f, 0.f, 0.f, 0.f};
  #pragma unroll
  for (int i = 0; i < 4; i++)
    #pragma unroll
    for (int j = 0; j < 4; j++) acc[i][j] = z4;

  for (int kt = 0; kt < Kslice; kt += 32){
    int4 a0 = *(const int4*)(Ab + (size_t)(m0+srow)*lda + kt + scol);
    int4 a1 = *(const int4*)(Ab + (size_t)(m0+64+srow)*lda + kt + scol);
    int4 b0 = *(const int4*)(Bb + (size_t)(n0+srow)*ldb + kt + scol);
    int4 b1 = *(const int4*)(Bb + (size_t)(n0+64+srow)*ldb + kt + scol);
    __syncthreads();
    *(int4*)&As[srow*32 + scol] = a0;
    *(int4*)&As[(64+srow)*32 + scol] = a1;
    *(int4*)&Bs[srow*32 + scol] = b0;
    *(int4*)&Bs[(64+srow)*32 + scol] = b1;
    __syncthreads();
    short8 af[4], bf[4];
    #pragma unroll
    for (int i = 0; i < 4; i++) af[i] = *(const short8*)&As[(wr*64 + i*16 + lr)*32 + lk*8];
    #pragma unroll
    for (int j = 0; j < 4; j++) bf[j] = *(const short8*)&Bs[(wc*64 + j*16 + lr)*32 + lk*8];
    #pragma unroll
    for (int i = 0; i < 4; i++)
      #pragma unroll
      for (int j = 0; j < 4; j++)
        acc[i][j] = __builtin_amdgcn_mfma_f32_16x16x32_bf16(af[i], bf[j], acc[i][j], 0, 0, 0);
  }
  size_t cbase = (size_t)(EPI == 3 ? bz : batch) * sC;
  #pragma unroll
  for (int i = 0; i < 4; i++){
    int rbase = m0 + wr*64 + i*16 + lk*4;
    #pragma unroll
    for (int j = 0; j < 4; j++){
      int cc = n0 + wc*64 + j*16 + lr;
      #pragma unroll
      for (int jj = 0; jj < 4; jj++){
        float v = acc[i][j][jj];
        int rr = rbase + jj;
        if (EPI == 0 || EPI == 3) C[cbase + (size_t)rr*ldc + cc] = v;
        else {
          float vv = v + ep1[cc] + ep2[(size_t)(rr & 4095)*DD + cc];
          Cb[(size_t)rr*ldc + cc] = f2bf(vv);
        }
      }
    }
  }
}

// ---------------- skinny MFMA GEMM: C(64 x N) = A(64 x K) @ Bt(N x K)^T ----------------
// ACT: 0 none, 1 relu, 2 gelu.  RES: 0 store, 1 atomicAdd.  OUTB: 0 fp32 C, 1 bf16 Cb.
// grid: (N/64, ksplit). Bias applied only on ks==0.
template<int ACT, int RES, int OUTB>
__global__ __launch_bounds__(256) void k_mf64(
    const u16* __restrict__ A, const u16* __restrict__ Bt,
    const float* __restrict__ bias, float* __restrict__ C, u16* __restrict__ Cb,
    int K, int kper, int ldc, float alpha)
{
  int n0 = blockIdx.x*64;
  int ks = blockIdx.y;
  int kbeg = ks*kper;
  __shared__ __align__(16) u16 As[64*80];
  __shared__ __align__(16) u16 Bs[64*80];
  int t = threadIdx.x, lane = t & 63, w = t >> 6;
  int lr = lane & 15, lk = lane >> 4;
  int sr = t >> 2, sc = (t & 3)*8;
  float4v acc[4];
  float4v z4 = {0.f,0.f,0.f,0.f};
  acc[0]=z4; acc[1]=z4; acc[2]=z4; acc[3]=z4;
  for (int kc = kbeg; kc < kbeg + kper; kc += 64){
    int4 a0 = *(const int4*)(A + (size_t)sr*K + kc + sc);
    int4 a1 = *(const int4*)(A + (size_t)sr*K + kc + 32 + sc);
    int4 b0 = *(const int4*)(Bt + (size_t)(n0+sr)*K + kc + sc);
    int4 b1 = *(const int4*)(Bt + (size_t)(n0+sr)*K + kc + 32 + sc);
    __syncthreads();
    *(int4*)&As[sr*80 + sc] = a0;
    *(int4*)&As[sr*80 + 32 + sc] = a1;
    *(int4*)&Bs[sr*80 + sc] = b0;
    *(int4*)&Bs[sr*80 + 32 + sc] = b1;
    __syncthreads();
    #pragma unroll
    for (int s = 0; s < 2; s++){
      short8 af = *(const short8*)&As[(w*16+lr)*80 + s*32 + lk*8];
      #pragma unroll
      for (int nf = 0; nf < 4; nf++){
        short8 bf8 = *(const short8*)&Bs[(nf*16+lr)*80 + s*32 + lk*8];
        acc[nf] = __builtin_amdgcn_mfma_f32_16x16x32_bf16(af, bf8, acc[nf], 0, 0, 0);
      }
    }
  }
  #pragma unroll
  for (int nf = 0; nf < 4; nf++){
    int col = n0 + nf*16 + lr;
    float bsv = (bias && ks == 0) ? bias[col] : 0.f;
    #pragma unroll
    for (int jj = 0; jj < 4; jj++){
      int row = w*16 + lk*4 + jj;
      float v = acc[nf][jj]*alpha + bsv;
      if (ACT == 1) v = fmaxf(v, 0.f);
      else if (ACT == 2) v = 0.5f*v*(1.f + tanhf(0.7978845608028654f*(v + 0.044715f*v*v*v)));
      size_t o = (size_t)row*ldc + col;
      if (OUTB == 1) Cb[o] = f2bf(v);
      else if (RES == 0) C[o] = v;
      else atomicAdd(&C[o], v);
    }
  }
}

// ---------------- gather + fp32 embed for the 64 selected tokens ----------------
__global__ __launch_bounds__(256) void k_gather(const float* __restrict__ feat, const float* __restrict__ Wtok,
    const float* __restrict__ btok, const float* __restrict__ pos_emb, const int* __restrict__ oidx,
    float* __restrict__ x)
{
  int bq = blockIdx.x, b = bq >> 4;
  int tok = oidx[bq];
  __shared__ float fs[CE];
  const float* fr = feat + ((size_t)b*TOK + tok) * CE;
  for (int i = threadIdx.x; i < CE; i += 256) fs[i] = fr[i];
  __syncthreads();
  for (int d = threadIdx.x; d < DD; d += 256){
    float acc = btok[d] + pos_emb[(size_t)tok*DD + d];
    for (int i = 0; i < CE; i++) acc += fs[i] * Wtok[(size_t)i*DD + d];
    x[(size_t)bq*DD + d] = acc;
  }
}

// ---------------- LayerNorm over 64 rows -> bf16 ----------------
__global__ __launch_bounds__(256) void k_ln64b(const float* __restrict__ x, const float* __restrict__ g,
    const float* __restrict__ b, u16* __restrict__ h)
{
  int bq = blockIdx.x, t = threadIdx.x;
  const float* xr = x + (size_t)bq*DD;
  float a0 = xr[t], a1 = xr[t+256];
  __shared__ float sr[4];
  float s = wred_sum(a0 + a1);
  if ((t & 63) == 0) sr[t >> 6] = s;
  __syncthreads();
  float mu = (sr[0]+sr[1]+sr[2]+sr[3]) * (1.f/DD);
  float d0 = a0 - mu, d1 = a1 - mu;
  __syncthreads();
  float q = wred_sum(d0*d0 + d1*d1);
  if ((t & 63) == 0) sr[t >> 6] = q;
  __syncthreads();
  float var = (sr[0]+sr[1]+sr[2]+sr[3]) * (1.f/DD);
  float inv = rsqrtf(var + 1e-5f);
  h[(size_t)bq*DD + t]     = f2bf(d0*inv*g[t]     + b[t]);
  h[(size_t)bq*DD + t+256] = f2bf(d1*inv*g[t+256] + b[t+256]);
}

// ---------------- small fp32 GEMM (kept for rot6d head, N=978) ----------------
template<int ACT, int RES>
__global__ __launch_bounds__(256) void k_smallmm(
    const float* __restrict__ A, const float* __restrict__ Bm,
    const float* __restrict__ bias, float* __restrict__ C,
    int N, int K, int lda, int ldb, int ldc, float alpha)
{
  __shared__ float As[16*256];
  int t = threadIdx.x;
  int m0 = blockIdx.y * 16;
  int col = blockIdx.x * 64 + (t & 63);
  int w = t >> 6;
  int kper = K / gridDim.z;
  int kbeg = blockIdx.z * kper;
  float acc[4] = {0.f, 0.f, 0.f, 0.f};
  for (int kc = kbeg; kc < kbeg + kper; kc += 256){
    __syncthreads();
    for (int idx = t; idx < 4096; idx += 256){
      int r = idx >> 8, k = idx & 255;
      As[idx] = A[(size_t)(m0+r)*lda + kc + k];
    }
    __syncthreads();
    if (col < N){
      #pragma unroll 4
      for (int k = 0; k < 256; k++){
        float bv = Bm[(size_t)(kc+k)*ldb + col];
        acc[0] += As[(w*4+0)*256 + k] * bv;
        acc[1] += As[(w*4+1)*256 + k] * bv;
        acc[2] += As[(w*4+2)*256 + k] * bv;
        acc[3] += As[(w*4+3)*256 + k] * bv;
      }
    }
  }
  if (col < N){
    float bsv = (bias && blockIdx.z == 0) ? bias[col] : 0.f;
    #pragma unroll
    for (int i = 0; i < 4; i++){
      float v = acc[i]*alpha + bsv;
      if (ACT == 1) v = fmaxf(v, 0.f);
      size_t o = (size_t)(m0 + w*4 + i)*ldc + col;
      if (RES == 0) C[o] = v;
      else atomicAdd(&C[o], v);
    }
  }
}

// ---------------- z[bq][h][d] = sum_dh u[bq][h*32+dh] * Wk[d][h*32+dh]  (bf16 out) ----------------
__global__ __launch_bounds__(256) void k_zker(const float* __restrict__ u, const float* __restrict__ Wk, u16* __restrict__ z){
  int ds = blockIdx.x, h = blockIdx.y, t = threadIdx.x;
  __shared__ float us[64*33];
  __shared__ float wks[128*33];
  for (int idx = t; idx < 2048; idx += 256){ int bq = idx >> 5, dh = idx & 31; us[bq*33+dh] = u[(size_t)bq*DD + h*32 + dh]; }
  for (int idx = t; idx < 4096; idx += 256){ int r = idx >> 5, dh = idx & 31; wks[r*33+dh] = Wk[(size_t)(ds*128+r)*DD + h*32 + dh]; }
  __syncthreads();
  for (int oi = t; oi < 8192; oi += 256){
    int d = oi & 127, bq = oi >> 7;
    float acc = 0.f;
    #pragma unroll
    for (int dh = 0; dh < 32; dh++) acc += us[bq*33+dh] * wks[d*33+dh];
    z[((size_t)bq*HH + h)*DD + ds*128 + d] = f2bf(acc);
  }
}

// ---------------- softmax over 4096, fp32 in -> bf16 probs ----------------
__global__ __launch_bounds__(256) void k_softmax(const float* __restrict__ lg, u16* __restrict__ att){
  int row = blockIdx.x, t = threadIdx.x;
  const float* p = lg + (size_t)row*TOK;
  float v[16]; float mx = -1e30f;
  #pragma unroll
  for (int i = 0; i < 16; i++){ v[i] = p[t + i*256]; mx = fmaxf(mx, v[i]); }
  mx = wred_max(mx);
  __shared__ float sm[4]; __shared__ float ssum[4];
  if ((t & 63) == 0) sm[t >> 6] = mx;
  __syncthreads();
  mx = fmaxf(fmaxf(sm[0], sm[1]), fmaxf(sm[2], sm[3]));
  float s = 0.f;
  #pragma unroll
  for (int i = 0; i < 16; i++){ v[i] = expf(v[i] - mx); s += v[i]; }
  s = wred_sum(s);
  if ((t & 63) == 0) ssum[t >> 6] = s;
  __syncthreads();
  s = ssum[0]+ssum[1]+ssum[2]+ssum[3];
  float inv = 1.f / s;
  u16* q = att + (size_t)row*TOK;
  #pragma unroll
  for (int i = 0; i < 16; i++) q[t + i*256] = f2bf(v[i]*inv);
}

// ---------------- o_pre[bq][h*32+dh] = sum_D (Σ_s P)[bq][h][D] * Wv[D][h*32+dh]  (bf16 out) ----------------
__global__ __launch_bounds__(256) void k_ovp(const float* __restrict__ P, const float* __restrict__ Wv, u16* __restrict__ op){
  int bg = blockIdx.x, h = blockIdx.y, t = threadIdx.x;
  __shared__ float wvs[128*33];
  __shared__ float cs[16*129];
  int dh = t & 31, bl = t >> 5;
  float acc0 = 0.f, acc1 = 0.f;
  for (int Dc = 0; Dc < DD; Dc += 128){
    __syncthreads();
    for (int idx = t; idx < 4096; idx += 256){ int r = idx >> 5, q = idx & 31; wvs[r*33+q] = Wv[(size_t)(Dc+r)*DD + h*32 + q]; }
    for (int idx = t; idx < 2048; idx += 256){
      int r = idx >> 7, k = idx & 127;
      size_t base = ((size_t)(bg*8))*((size_t)QH*DD) + (size_t)(r*16+h)*DD + Dc + k;
      float s = 0.f;
      #pragma unroll
      for (int sp = 0; sp < 8; sp++) s += P[base + (size_t)sp*((size_t)QH*DD)];
      cs[r*129+k] = s;
    }
    __syncthreads();
    #pragma unroll 4
    for (int k = 0; k < 128; k++){
      float wv = wvs[k*33+dh];
      acc0 += cs[bl*129 + k] * wv;
      acc1 += cs[(bl+8)*129 + k] * wv;
    }
  }
  op[(size_t)(bg*16+bl)*DD + h*32 + dh] = f2bf(acc0);
  op[(size_t)(bg*16+bl+8)*DD + h*32 + dh] = f2bf(acc1);
}

// ---------------- constants for pose head (wave per output d) ----------------
__global__ __launch_bounds__(256) void k_cvec(const float* __restrict__ pW1, const float* __restrict__ pb1,
    const float* __restrict__ ibp, float* __restrict__ cvec)
{
  int d = blockIdx.x*4 + (threadIdx.x >> 6);
  int ln = threadIdx.x & 63;
  float acc = 0.f;
  for (int i = ln; i < NJ*6; i += 64) acc += ibp[i] * pW1[(size_t)(DD+i)*DD + d];
  acc = wred_sum(acc);
  if (ln == 0) cvec[d] = acc + pb1[d];
}
__global__ __launch_bounds__(256) void k_cvec2(const float* __restrict__ pb2, const float* __restrict__ ibp, float* __restrict__ cv){
  int j = blockIdx.x*256 + threadIdx.x;
  if (j < NJ*6) cv[j] = pb2[j] + ibp[j];
}

// ---------------- final heads + Gram-Schmidt + assembly ----------------
__global__ __launch_bounds__(256) void k_final(
    const float* __restrict__ h_off, const float* __restrict__ h_d, const float* __restrict__ h_s,
    const float* __restrict__ rot6d,
    const float* __restrict__ offW2, const float* __restrict__ offb2,
    const float* __restrict__ dW2, const float* __restrict__ db2,
    const float* __restrict__ sW2, const float* __restrict__ sb2,
    const float* __restrict__ K_cam, const float* __restrict__ useful,
    const float* __restrict__ maskf, const float* __restrict__ colf, const float* __restrict__ rowf,
    float* __restrict__ out)
{
  int bq = blockIdx.x, t = threadIdx.x, b = bq >> 4;
  float po0 = 0.f, po1 = 0.f, pd = 0.f, ps[11];
  #pragma unroll
  for (int j = 0; j < 11; j++) ps[j] = 0.f;
  for (int i = t; i < DD; i += 256){
    float ho = h_off[(size_t)bq*DD + i];
    float hd = h_d[(size_t)bq*DD + i];
    float hs = h_s[(size_t)bq*DD + i];
    po0 += ho*offW2[i*2]; po1 += ho*offW2[i*2+1];
    pd += hd*dW2[i];
    #pragma unroll
    for (int j = 0; j < 11; j++) ps[j] += hs*sW2[i*11+j];
  }
  __shared__ float sred[4][14];
  __shared__ float sout[14];
  int wv = t >> 6, ln = t & 63;
  float vals[14];
  vals[0] = po0; vals[1] = po1; vals[2] = pd;
  #pragma unroll
  for (int j = 0; j < 11; j++) vals[3+j] = ps[j];
  #pragma unroll
  for (int kk = 0; kk < 14; kk++){
    float r = wred_sum(vals[kk]);
    if (ln == 0) sred[wv][kk] = r;
  }
  __syncthreads();
  if (t < 14) sout[t] = sred[0][t]+sred[1][t]+sred[2][t]+sred[3][t];
  __syncthreads();
  float m = maskf[bq];
  if (t == 0){
    float off0 = sout[0] + offb2[0], off1 = sout[1] + offb2[1];
    float draw = sout[2] + db2[0];
    float l0 = (colf[bq] + 0.5f + off0) * 14.0f;
    float l1 = (rowf[bq] + 0.5f + off1) * 14.0f;
    float fx = K_cam[b*9+0], cx = K_cam[b*9+2], fy = K_cam[b*9+4], cy = K_cam[b*9+5];
    float dist = fx / fmaxf(expf(draw), 1e-5f);
    float tx = (l0 - cx) / fx * dist, ty = (l1 - cy) / fy * dist;
    float* o = out + (size_t)bq*OUTW;
    o[0] = l0*m; o[1] = l1*m; o[2] = off0*m; o[3] = off1*m; o[4] = dist*m;
    o[5] = tx*m; o[6] = ty*m; o[7] = dist*m;
    #pragma unroll
    for (int j = 0; j < 11; j++){ float sp = sout[3+j] + sb2[j]; o[8+j] = m / (1.f + expf(-sp)); }
  }
  if (t < NJ){
    const float* rp = rot6d + (size_t)bq*(NJ*6) + t*6;
    float a0 = rp[0], b0 = rp[1], a1 = rp[2], b1 = rp[3], a2 = rp[4], b2 = rp[5];
    float n0 = sqrtf(a0*a0 + a1*a1 + a2*a2);
    float i0 = 1.f / (n0 + 1e-8f);
    float u00 = a0*i0, u01 = a1*i0, u02 = a2*i0;
    float dt = b0*u00 + b1*u01 + b2*u02;
    float v0 = b0 - dt*u00, v1 = b1 - dt*u01, v2 = b2 - dt*u02;
    float n1 = sqrtf(v0*v0 + v1*v1 + v2*v2);
    float i1 = 1.f / (n1 + 1e-8f);
    float u10 = v0*i1, u11 = v1*i1, u12 = v2*i1;
    float u20 = u01*u12 - u02*u11;
    float u21 = u02*u10 - u00*u12;
    float u22 = u00*u11 - u01*u10;
    float um = useful[t], om = 1.f - um;
    float R00 = um*u00 + om, R01 = um*u10,      R02 = um*u20;
    float R10 = um*u01,      R11 = um*u11 + om, R12 = um*u21;
    float R20 = um*u02,      R21 = um*u12,      R22 = um*u22 + om;
    float* o = out + (size_t)bq*OUTW + 19 + t*9;
    o[0] = R00*m; o[1] = R01*m; o[2] = R02*m;
    o[3] = R10*m; o[4] = R11*m; o[5] = R12*m;
    o[6] = R20*m; o[7] = R21*m; o[8] = R22*m;
  }
}

extern "C" void kernel_launch(void* const* d_in, const int* in_sizes, int n_in,
                              void* d_out, int out_size, void* d_ws, size_t ws_size,
                              hipStream_t stream)
{
  const float* feat   = (const float*)d_in[0];
  const float* scores = (const float*)d_in[1];
  const float* K_cam  = (const float*)d_in[2];
  const float* pos_emb= (const float*)d_in[3];
  const float* Wtok   = (const float*)d_in[4];
  const float* btok   = (const float*)d_in[5];
  const float* Wq     = (const float*)d_in[6];
  const float* Wk     = (const float*)d_in[7];
  const float* Wv     = (const float*)d_in[8];
  const float* Wo     = (const float*)d_in[9];
  const float* g1     = (const float*)d_in[10];
  const float* b1n    = (const float*)d_in[11];
  const float* W1     = (const float*)d_in[12];
  const float* bf1    = (const float*)d_in[13];
  const float* W2     = (const float*)d_in[14];
  const float* bf2    = (const float*)d_in[15];
  const float* g2     = (const float*)d_in[16];
  const float* b2n    = (const float*)d_in[17];
  const float* offW1  = (const float*)d_in[18];
  const float* offb1  = (const float*)d_in[19];
  const float* offW2  = (const float*)d_in[20];
  const float* offb2  = (const float*)d_in[21];
  const float* dW1    = (const float*)d_in[22];
  const float* db1    = (const float*)d_in[23];
  const float* dW2    = (const float*)d_in[24];
  const float* db2    = (const float*)d_in[25];
  const float* sW1    = (const float*)d_in[26];
  const float* sb1    = (const float*)d_in[27];
  const float* sW2    = (const float*)d_in[28];
  const float* sb2    = (const float*)d_in[29];
  const float* pW1    = (const float*)d_in[30];
  const float* pb1    = (const float*)d_in[31];
  const float* pW2    = (const float*)d_in[32];
  const float* pb2    = (const float*)d_in[33];
  const float* ibp    = (const float*)d_in[34];
  const float* useful = (const float*)d_in[35];
  float* out = (float*)d_out;

  char* wsp = (char*)d_ws;
  size_t off = 0;
  auto alloc = [&](size_t bytes)->char*{
    char* p = wsp + off;
    off += (bytes + 255) & ~((size_t)255);
    return p;
  };
  int*   t_idx  = (int*)  alloc(BKQ*4);
  float* t_mask = (float*)alloc(BKQ*4);
  float* t_col  = (float*)alloc(BKQ*4);
  float* t_row  = (float*)alloc(BKQ*4);
  u16*   feat_bf= (u16*)  alloc((size_t)BB*TOK*CE*2);
  u16*   wtokT  = (u16*)  alloc((size_t)DD*CE*2);
  u16*   ctx_bf = (u16*)  alloc((size_t)BB*TOK*DD*2);
  u16*   ctxT_bf= (u16*)  alloc((size_t)BB*TOK*DD*2);
  u16*   wqT    = (u16*)  alloc((size_t)LL*DD*DD*2);
  u16*   woT    = (u16*)  alloc((size_t)LL*DD*DD*2);
  u16*   w1T    = (u16*)  alloc((size_t)LL*DD*MM*2);
  u16*   w2T    = (u16*)  alloc((size_t)LL*MM*DD*2);
  u16*   offT   = (u16*)  alloc((size_t)DD*DD*2);
  u16*   dT     = (u16*)  alloc((size_t)DD*DD*2);
  u16*   sT     = (u16*)  alloc((size_t)DD*DD*2);
  u16*   pT     = (u16*)  alloc((size_t)DD*DD*2);
  float* x      = (float*)alloc((size_t)BKQ*DD*4);
  u16*   x_bf   = (u16*)  alloc((size_t)BKQ*DD*2);
  u16*   h_bf   = (u16*)  alloc((size_t)BKQ*DD*2);
  float* u      = (float*)alloc((size_t)BKQ*DD*4);
  u16*   z_bf   = (u16*)  alloc((size_t)BKQ*HH*DD*2);
  float* logits = (float*)alloc((size_t)BB*QH*TOK*4);   // reused as att@V partials after softmax
  u16*   att_bf = (u16*)  alloc((size_t)BB*QH*TOK*2);
  u16*   o_pre  = (u16*)  alloc((size_t)BKQ*DD*2);
  u16*   mid_bf = (u16*)  alloc((size_t)BKQ*MM*2);
  float* h_off  = (float*)alloc((size_t)BKQ*DD*4);
  float* h_d    = (float*)alloc((size_t)BKQ*DD*4);
  float* h_s    = (float*)alloc((size_t)BKQ*DD*4);
  float* h_p    = (float*)alloc((size_t)BKQ*DD*4);
  float* cvec   = (float*)alloc(DD*4);
  float* cvec2  = (float*)alloc(NJ*6*4);
  float* rot6d  = (float*)alloc((size_t)BKQ*NJ*6*4);
  if (off > ws_size) return;

  const float scale = 0.17677669529663687f; // 1/sqrt(32)

  k_nms_topk<<<BB, 256, 0, stream>>>(scores, t_idx, t_mask, t_col, t_row);
  k_cvt_bf16<<<3072, 256, 0, stream>>>(feat, feat_bf, BB*TOK*CE/4);
  k_tconv_f2b<<<dim3(DD/32, CE/32), 256, 0, stream>>>(Wtok, wtokT, CE, DD);
  // one-time weight prep: transpose+convert to bf16 (N x K layout)
  k_tconvL<<<dim3(16,16,LL), 256, 0, stream>>>(Wq, wqT, DD, DD);
  k_tconvL<<<dim3(16,16,LL), 256, 0, stream>>>(Wo, woT, DD, DD);
  k_tconvL<<<dim3(64,16,LL), 256, 0, stream>>>(W1, w1T, DD, MM);
  k_tconvL<<<dim3(16,64,LL), 256, 0, stream>>>(W2, w2T, MM, DD);
  k_tconv_f2b<<<dim3(16,16), 256, 0, stream>>>(offW1, offT, DD, DD);
  k_tconv_f2b<<<dim3(16,16), 256, 0, stream>>>(dW1,   dT,   DD, DD);
  k_tconv_f2b<<<dim3(16,16), 256, 0, stream>>>(sW1,   sT,   DD, DD);
  k_tconv_f2b<<<dim3(16,16), 256, 0, stream>>>(pW1,   pT,   DD, DD);
  // ctx = feat @ Wtok + btok + pos_emb   (bf16 out)
  k_gemm_bt<2><<<dim3(DD/128, (BB*TOK)/128, 1), 256, 0, stream>>>(
      feat_bf, wtokT, nullptr, ctx_bf, btok, pos_emb, CE, CE, CE, DD, 0, 0, 0, 1);
  k_transp_b<<<dim3(DD/32, TOK/32, BB), 256, 0, stream>>>(ctx_bf, ctxT_bf, TOK, DD);
  k_gather<<<BKQ, 256, 0, stream>>>(feat, Wtok, btok, pos_emb, t_idx, x);

  for (int l = 0; l < LL; l++){
    // u = LN1(x) @ Wq * scale
    k_ln64b<<<BKQ, 256, 0, stream>>>(x, g1 + l*DD, b1n + l*DD, h_bf);
    k_mf64<0,0,0><<<dim3(8,1), 256, 0, stream>>>(h_bf, wqT + (size_t)l*DD*DD, nullptr, u, nullptr, DD, DD, DD, scale);
    k_zker<<<dim3(4,HH), 256, 0, stream>>>(u, Wk + (size_t)l*DD*DD, z_bf);
    // logits[b] = Z_b (256x512) @ ctx_b^T
    k_gemm_bt<0><<<dim3(TOK/128, QH/128, BB), 256, 0, stream>>>(
        z_bf, ctx_bf, logits, nullptr, nullptr, nullptr,
        DD, DD, DD, TOK, (long)QH*DD, (long)TOK*DD, (long)QH*TOK, 1);
    k_softmax<<<BB*QH, 256, 0, stream>>>(logits, att_bf);
    // partials[b*8+s] = att_b @ ctxT_b^T over K-slice s  (reuses logits buffer)
    k_gemm_bt<3><<<dim3(DD/128, QH/128, BB*8), 256, 0, stream>>>(
        att_bf, ctxT_bf, logits, nullptr, nullptr, nullptr,
        TOK/8, TOK, TOK, DD, (long)QH*TOK, (long)DD*TOK, (long)QH*DD, 8);
    k_ovp<<<dim3(4,HH), 256, 0, stream>>>(logits, Wv + (size_t)l*DD*DD, o_pre);
    // x += o_pre @ Wo   (ksplit=4, atomic)
    k_mf64<0,1,0><<<dim3(8,4), 256, 0, stream>>>(o_pre, woT + (size_t)l*DD*DD, nullptr, x, nullptr, DD, DD/4, DD, 1.f);
    // mid = gelu(LN2(x) @ W1 + bf1)  -> bf16
    k_ln64b<<<BKQ, 256, 0, stream>>>(x, g2 + l*DD, b2n + l*DD, h_bf);
    k_mf64<2,0,1><<<dim3(MM/64,1), 256, 0, stream>>>(h_bf, w1T + (size_t)l*DD*MM, bf1 + l*MM, nullptr, mid_bf, DD, DD, MM, 1.f);
    // x += mid @ W2 + bf2  (ksplit=4, atomic)
    k_mf64<0,1,0><<<dim3(8,4), 256, 0, stream>>>(mid_bf, w2T + (size_t)l*MM*DD, bf2 + l*DD, x, nullptr, MM, MM/4, DD, 1.f);
  }

  // heads
  k_cvt_bf16<<<32, 256, 0, stream>>>(x, x_bf, BKQ*DD/4);
  k_cvec<<<DD/4, 256, 0, stream>>>(pW1, pb1, ibp, cvec);
  k_mf64<1,0,0><<<dim3(8,1), 256, 0, stream>>>(x_bf, offT, offb1, h_off, nullptr, DD, DD, DD, 1.f);
  k_mf64<1,0,0><<<dim3(8,1), 256, 0, stream>>>(x_bf, dT,   db1,   h_d,   nullptr, DD, DD, DD, 1.f);
  k_mf64<1,0,0><<<dim3(8,1), 256, 0, stream>>>(x_bf, sT,   sb1,   h_s,   nullptr, DD, DD, DD, 1.f);
  k_mf64<1,0,0><<<dim3(8,1), 256, 0, stream>>>(x_bf, pT,   cvec,  h_p,   nullptr, DD, DD, DD, 1.f);
  k_cvec2<<<4, 256, 0, stream>>>(pb2, ibp, cvec2);
  k_smallmm<0,0><<<dim3(16,4,1), 256, 0, stream>>>(h_p, pW2, cvec2, rot6d, NJ*6, DD, DD, NJ*6, NJ*6, 1.f);
  k_final<<<BKQ, 256, 0, stream>>>(h_off, h_d, h_s, rot6d, offW2, offb2, dW2, db2, sW2, sb2,
                                   K_cam, useful, t_mask, t_col, t_row, out);
}